// Round 3
// baseline (768.295 us; speedup 1.0000x reference)
//
#include <hip/hip_runtime.h>
#include <hip/hip_bf16.h>

#define Bb 4
#define Hh 8
#define Ll 8192
#define Dd 64
#define Cc 256
#define Ww 32
#define TL 128   // tokens per k1 block

// ---------------- k1: dists GEMM + argmax buckets + loss partials + dist_T write ----------------
// grid (Ll/TL, hStep, bStep), block 256. thread tile: 8 tokens x 8 clusters, float4 LDS reads.
__global__ __launch_bounds__(256) void k1_gemm(const float* __restrict__ x,
                                               const float* __restrict__ means,
                                               float* __restrict__ distT,
                                               int* __restrict__ buckets,
                                               float* __restrict__ lossP,
                                               int b0, int h0) {
    __shared__ __align__(16) float ms[128 * 68];   // half of means[h] (34 KB)
    __shared__ __align__(16) float xs[TL * 68];    // token tile (34 KB)
    __shared__ float pv[TL * 4];
    __shared__ int   pc[TL * 4];
    __shared__ float msq[256];
    __shared__ float lossAcc;

    const int tid = threadIdx.x;
    const int hl  = blockIdx.y, bz = blockIdx.z;
    const int h   = h0 + hl,    b  = b0 + bz;
    const int l0  = blockIdx.x * TL;
    const int tg  = tid & 15;    // tokens t = tg + 16*jt, jt<8
    const int cg  = tid >> 4;    // clusters c = cg + 16*jl + 128*p, jl<8

    if (tid == 0) lossAcc = 0.f;

    const float* xbase = x + (((size_t)(b * Hh + h)) * Ll + l0) * Dd;
    for (int j = tid; j < TL * 16; j += 256) {
        int t = j >> 4, k4 = (j & 15) << 2;
        *(float4*)&xs[t * 68 + k4] = *(const float4*)(xbase + t * Dd + k4);
    }

    float bvr[8]; int bcr[8];
    #pragma unroll
    for (int jt = 0; jt < 8; jt++) { bvr[jt] = -3.4e38f; bcr[jt] = 0; }

    const size_t pbase = ((size_t)(bz * gridDim.y + hl)) * Cc;

    for (int p = 0; p < 2; p++) {
        __syncthreads();  // covers xs staging (p=0) / protects ms from prev-pass readers (p=1)
        const float* mbase = means + ((size_t)h * Cc + p * 128) * Dd;
        for (int j = tid; j < 128 * 16; j += 256) {
            int r = j >> 4, k4 = (j & 15) << 2;
            *(float4*)&ms[r * 68 + k4] = *(const float4*)(mbase + r * Dd + k4);
        }
        __syncthreads();
        if (tid < 128) {  // |m_c|^2 for the loss
            float s = 0.f;
            #pragma unroll
            for (int k = 0; k < 64; k += 4) {
                float4 m = *(const float4*)&ms[tid * 68 + k];
                s = fmaf(m.x, m.x, s); s = fmaf(m.y, m.y, s);
                s = fmaf(m.z, m.z, s); s = fmaf(m.w, m.w, s);
            }
            msq[(p << 7) + tid] = s;
        }

        float acc[8][8];
        #pragma unroll
        for (int jt = 0; jt < 8; jt++)
            #pragma unroll
            for (int jl = 0; jl < 8; jl++) acc[jt][jl] = 0.f;

        #pragma unroll 4
        for (int k = 0; k < 64; k += 4) {
            float4 xa[8];
            #pragma unroll
            for (int jt = 0; jt < 8; jt++) xa[jt] = *(const float4*)&xs[(tg + 16 * jt) * 68 + k];
            #pragma unroll
            for (int jl = 0; jl < 8; jl++) {
                float4 m = *(const float4*)&ms[(cg + 16 * jl) * 68 + k];
                #pragma unroll
                for (int jt = 0; jt < 8; jt++) {
                    float a = acc[jt][jl];
                    a = fmaf(xa[jt].x, m.x, a); a = fmaf(xa[jt].y, m.y, a);
                    a = fmaf(xa[jt].z, m.z, a); a = fmaf(xa[jt].w, m.w, a);
                    acc[jt][jl] = a;
                }
            }
        }

        // dist_T writes + running per-thread argmax (c strictly ascending across jl and p)
        #pragma unroll
        for (int jt = 0; jt < 8; jt++) {
            int t = tg + 16 * jt;
            #pragma unroll
            for (int jl = 0; jl < 8; jl++) {
                int cl = cg + 16 * jl + (p << 7);
                float v = acc[jt][jl];
                distT[(pbase + cl) * Ll + l0 + t] = v;
                if (v > bvr[jt]) { bvr[jt] = v; bcr[jt] = cl; }
            }
        }
    }

    // merge argmax: in-wave across the 4 cluster-groups of this wave, then LDS across waves
    #pragma unroll
    for (int jt = 0; jt < 8; jt++) {
        float bv = bvr[jt]; int bc = bcr[jt];
        #pragma unroll
        for (int off = 16; off <= 32; off <<= 1) {
            float ov = __shfl_xor(bv, off);
            int   oc = __shfl_xor(bc, off);
            if (ov > bv || (ov == bv && oc < bc)) { bv = ov; bc = oc; }
        }
        if ((tid & 48) == 0) { int t = tg + 16 * jt; pv[t * 4 + (tid >> 6)] = bv; pc[t * 4 + (tid >> 6)] = bc; }
    }
    __syncthreads();

    if (tid < TL) {
        int t = tid;
        float bv = pv[t * 4]; int bc = pc[t * 4];
        #pragma unroll
        for (int g = 1; g < 4; g++) {
            float v = pv[t * 4 + g]; int c2 = pc[t * 4 + g];
            if (v > bv || (v == bv && c2 < bc)) { bv = v; bc = c2; }
        }
        float ss = 0.f;
        #pragma unroll
        for (int k = 0; k < 64; k += 4) {
            float4 u = *(const float4*)&xs[t * 68 + k];
            ss = fmaf(u.x, u.x, ss); ss = fmaf(u.y, u.y, ss);
            ss = fmaf(u.z, u.z, ss); ss = fmaf(u.w, u.w, ss);
        }
        buckets[((size_t)(b * Hh + h)) * Ll + l0 + t] = bc;
        atomicAdd(&lossAcc, ss - 2.f * bv + msq[bc]);
    }
    __syncthreads();
    if (tid == 0) lossP[(b * Hh + h) * (Ll / TL) + blockIdx.x] = lossAcc;
}

// ---------------- k2: exact top-32 via ballot binary-search threshold ----------------
// Any T with count(keys >= T) >= 32 gives an exact candidate superset of the top-32.
// Binary-search T on the per-thread chunk maxima: countMax(T) >= 48 guarantees >= 48
// candidates (each qualifying chunk contributes >= 1). Probes are register+ballot only
// (~10 instr + 1 barrier each) -- replaces the LDS-pipe-bound 256-iter rank loop (r2)
// and the hot-bin LDS atomic histogram (r1), both ~30 us of selection overhead.
__device__ __forceinline__ unsigned int f2key(float f) {
    unsigned int u = __float_as_uint(f);
    return (u & 0x80000000u) ? ~u : (u | 0x80000000u);
}

#define K2CAP 1024
#define K2MAXIT 34

__global__ __launch_bounds__(256) void k2_topk(const float* __restrict__ distT,
                                               float* __restrict__ outIdx,
                                               int b0, int h0) {
    __shared__ unsigned int cntIt[K2MAXIT];
    __shared__ unsigned int sCnt;
    __shared__ unsigned int candK[K2CAP];
    __shared__ int candI[K2CAP];
    __shared__ int comb[32];

    const int tid = threadIdx.x;
    const int c = blockIdx.x, hl = blockIdx.y, bz = blockIdx.z;
    const int h = h0 + hl, b = b0 + bz;
    const float* col = distT + ((size_t)((bz * gridDim.y + hl) * Cc + c)) * Ll;

    unsigned int key[32];
    #pragma unroll
    for (int j = 0; j < 8; j++) {
        float4 v = *(const float4*)(col + j * 1024 + tid * 4);
        key[j * 4 + 0] = f2key(v.x); key[j * 4 + 1] = f2key(v.y);
        key[j * 4 + 2] = f2key(v.z); key[j * 4 + 3] = f2key(v.w);
    }

    unsigned int mx = 0u;
    #pragma unroll
    for (int j = 0; j < 32; j++) mx = (key[j] > mx) ? key[j] : mx;

    if (tid < K2MAXIT) cntIt[tid] = 0u;
    if (tid == 0) sCnt = 0u;
    __syncthreads();

    // binary search for T: invariant countMax(lo) >= 48, countMax(hi) < 48.
    // stop when countMax(lo) in [48, 192] or interval exhausted. All state uniform.
    unsigned int lo = 0u, hi = 0xFFFFFFFFu;
    unsigned int cLo = 256u;
    for (int it = 0; it < K2MAXIT && cLo > 192u && (hi - lo) > 1u; it++) {
        unsigned int mid = lo + ((hi - lo) >> 1);
        unsigned long long m = __ballot(mx >= mid);
        if ((tid & 63) == 0) atomicAdd(&cntIt[it], (unsigned int)__popcll(m));
        __syncthreads();
        unsigned int cm = cntIt[it];
        if (cm >= 48u) { lo = mid; cLo = cm; } else hi = mid;
    }
    const unsigned int T0 = lo;   // count(keys >= T0) >= cLo >= 48 >= 32

    // compact candidates (>= T0)
    #pragma unroll
    for (int j = 0; j < 32; j++) {
        if (key[j] >= T0) {
            unsigned int pos = atomicAdd(&sCnt, 1u);
            if (pos < K2CAP) {
                candK[pos] = key[j];
                candI[pos] = (j >> 2) * 1024 + tid * 4 + (j & 3);
            }
        }
    }
    __syncthreads();
    const int cnt = (int)sCnt;

    if (cnt > K2CAP) {
        // pathological tie flood: exact serial stable top-32
        if (tid == 0) {
            unsigned int bk[32]; int bi[32];
            for (int j = 0; j < 32; j++) { bk[j] = 0u; bi[j] = 0; }
            for (int i = 0; i < Ll; i++) {
                unsigned int kk = f2key(col[i]);
                if (kk > bk[31]) {           // strict: equal keys keep earlier (lower idx)
                    int p2 = 31;
                    while (p2 > 0 && kk > bk[p2 - 1]) {
                        bk[p2] = bk[p2 - 1]; bi[p2] = bi[p2 - 1]; p2--;
                    }
                    bk[p2] = kk; bi[p2] = i;
                }
            }
            for (int j = 0; j < 32; j++) comb[j] = bi[j];
        }
        __syncthreads();
    } else {
        // exact stable rank among candidates (== global rank for all top-32 elements)
        for (int i = tid; i < cnt; i += 256) {
            unsigned int k = candK[i]; int id = candI[i];
            int rk = 0;
            for (int j2 = 0; j2 < cnt; j2++) {
                unsigned int kj = candK[j2];
                rk += (kj > k || (kj == k && candI[j2] < id)) ? 1 : 0;
            }
            if (rk < 32) comb[rk] = id;
        }
        __syncthreads();
    }

    if (tid < Ww) {
        int v = comb[tid];
        int rank = 0;
        #pragma unroll
        for (int j = 0; j < Ww; j++) rank += (comb[j] < v);
        outIdx[(((size_t)(b * Hh + h)) * Cc + c) * Ww + rank] = (float)v;
    }
}

// ---------------- k3: counting sort by (h,cluster), then gather ----------------
__global__ __launch_bounds__(256) void k3_hist(const int* __restrict__ buckets,
                                               unsigned int* __restrict__ hist) {
    __shared__ unsigned int lh[256];
    const int tid = threadIdx.x;
    lh[tid] = 0;
    __syncthreads();
    int i = blockIdx.x * 256 + tid;
    int bk = buckets[i];
    atomicAdd(&lh[bk], 1u);
    __syncthreads();
    int h = (i >> 13) & 7;   // block spans 256 tokens of one (b,h)
    if (lh[tid]) atomicAdd(&hist[h * 256 + tid], lh[tid]);
}

__global__ __launch_bounds__(256) void k3_scan(const unsigned int* __restrict__ hist,
                                               unsigned int* __restrict__ offs,
                                               unsigned int* __restrict__ cursor) {
    __shared__ unsigned int ps[256];
    const int tid = threadIdx.x;
    unsigned int loc[8];
    unsigned s = 0;
    #pragma unroll
    for (int k = 0; k < 8; k++) { loc[k] = hist[tid * 8 + k]; s += loc[k]; }
    ps[tid] = s;
    __syncthreads();
    for (int off = 1; off < 256; off <<= 1) {
        unsigned v = (tid >= off) ? ps[tid - off] : 0;
        __syncthreads();
        ps[tid] += v;
        __syncthreads();
    }
    unsigned base = ps[tid] - s;  // exclusive
    #pragma unroll
    for (int k = 0; k < 8; k++) {
        offs[tid * 8 + k] = base;
        cursor[tid * 8 + k] = base;
        base += loc[k];
    }
    if (tid == 255) offs[2048] = ps[255];
}

__global__ __launch_bounds__(256) void k3_scatter(const int* __restrict__ buckets,
                                                  unsigned int* __restrict__ cursor,
                                                  unsigned int* __restrict__ sortedTok) {
    int i = blockIdx.x * 256 + threadIdx.x;
    int bk = buckets[i];
    int h = (i >> 13) & 7, b = i >> 16, l = i & 8191;
    unsigned pos = atomicAdd(&cursor[h * 256 + bk], 1u);
    sortedTok[pos] = (unsigned)((b << 13) | l);
}

// MLP-restructured gather: lane = (token-slot tl = lane>>4, dim-quad q = lane&15).
__global__ __launch_bounds__(256) void k3_gather(const float* __restrict__ x,
                                                 const float* __restrict__ means,
                                                 const unsigned int* __restrict__ offs,
                                                 const unsigned int* __restrict__ sortedTok,
                                                 float* __restrict__ outMeans) {
    __shared__ __align__(16) float part[4][64];
    const int tid = threadIdx.x;
    const int w = tid >> 6;          // wave 0..3
    const int lane = tid & 63;
    const int tl = lane >> 4;        // token slot within wave 0..3
    const int q  = lane & 15;        // dim quad 0..15 (handles d = 4q..4q+3)
    const int bin = blockIdx.x;
    const int h = bin >> 8, cc = bin & 255;
    const unsigned s0 = offs[bin], s1 = offs[bin + 1];
    const int n = (int)(s1 - s0);

    float4 a0 = make_float4(0.f, 0.f, 0.f, 0.f);
    float4 a1 = make_float4(0.f, 0.f, 0.f, 0.f);
    int j = w * 4 + tl;              // this slot handles j ≡ w*4+tl (mod 16)
    for (; j + 16 < n; j += 32) {    // 2 tokens in flight per slot
        unsigned e0 = sortedTok[s0 + j];
        unsigned e1 = sortedTok[s0 + j + 16];
        const float* p0 = x + (((size_t)((int)(e0 >> 13) * Hh + h)) * Ll + (e0 & 8191)) * Dd + q * 4;
        const float* p1 = x + (((size_t)((int)(e1 >> 13) * Hh + h)) * Ll + (e1 & 8191)) * Dd + q * 4;
        float4 v0 = *(const float4*)p0;
        float4 v1 = *(const float4*)p1;
        a0.x += v0.x; a0.y += v0.y; a0.z += v0.z; a0.w += v0.w;
        a1.x += v1.x; a1.y += v1.y; a1.z += v1.z; a1.w += v1.w;
    }
    for (; j < n; j += 16) {         // at most one leftover token per slot
        unsigned e = sortedTok[s0 + j];
        const float* p = x + (((size_t)((int)(e >> 13) * Hh + h)) * Ll + (e & 8191)) * Dd + q * 4;
        float4 v = *(const float4*)p;
        a0.x += v.x; a0.y += v.y; a0.z += v.z; a0.w += v.w;
    }
    a0.x += a1.x; a0.y += a1.y; a0.z += a1.z; a0.w += a1.w;

    // reduce across the 4 token slots (lane bits 4 and 5)
    #pragma unroll
    for (int off = 16; off <= 32; off <<= 1) {
        a0.x += __shfl_xor(a0.x, off);
        a0.y += __shfl_xor(a0.y, off);
        a0.z += __shfl_xor(a0.z, off);
        a0.w += __shfl_xor(a0.w, off);
    }
    if (tl == 0) *(float4*)&part[w][q * 4] = a0;
    __syncthreads();

    if (tid < 64) {
        const int d = tid;
        float s = part[0][d] + part[1][d] + part[2][d] + part[3][d];
        float t = s * s;
        #pragma unroll
        for (int off = 32; off; off >>= 1) t += __shfl_xor(t, off);
        float nrm = sqrtf(t);
        float outv = (n == 0) ? means[((size_t)(h * Cc + cc)) * Dd + d]
                              : s / fmaxf(nrm, 1e-12f);
        outMeans[((size_t)(h * Cc + cc)) * Dd + d] = outv;
    }
}

// ---------------- k4: loss reduction ----------------
__global__ __launch_bounds__(256) void k4_loss(const float* __restrict__ lossP,
                                               float* __restrict__ out) {
    __shared__ float red[256];
    const int tid = threadIdx.x;
    float s = 0.f;
    for (int i = tid; i < Bb * Hh * (Ll / TL); i += 256) s += lossP[i];
    red[tid] = s;
    __syncthreads();
    for (int off = 128; off; off >>= 1) {
        if (tid < off) red[tid] += red[tid + off];
        __syncthreads();
    }
    if (tid == 0)
        out[(size_t)Bb * Hh * Cc * Ww] = red[0] * (1e-4f / (float)((size_t)Bb * Hh * Ll * Dd));
}

extern "C" void kernel_launch(void* const* d_in, const int* in_sizes, int n_in,
                              void* d_out, int out_size, void* d_ws, size_t ws_size,
                              hipStream_t stream) {
    (void)in_sizes; (void)n_in; (void)out_size;
    const float* x = (const float*)d_in[0];
    const float* means = (const float*)d_in[1];
    float* out = (float*)d_out;

    char* ws = (char*)d_ws;
    float* lossP = (float*)ws;                              // 2048 floats (8 KB)
    int* buckets = (int*)(ws + 8192);                       // 1 MB
    unsigned int* hist = (unsigned int*)(ws + 8192 + 1048576);       // 2048
    unsigned int* offs = hist + 2048;                       // 2049
    unsigned int* cursor = offs + 2049;                     // 2048
    unsigned int* sortedTok = cursor + 2048;                // 262144 (1 MB)
    size_t base = 8192 + 1048576 + 4ull * (2048 + 2049 + 2048) + 4ull * 262144;
    base = (base + 255) & ~255ull;
    float* distT = (float*)(ws + base);
    const size_t perPlane = (size_t)Cc * Ll * 4;            // 8 MB per (b,h) plane

    int bStep = 4, hStep = 8;
    if (base + (size_t)bStep * hStep * perPlane > ws_size) bStep = 1;
    while (hStep > 1 && base + (size_t)bStep * hStep * perPlane > ws_size) hStep >>= 1;

    hipMemsetAsync(hist, 0, 2048 * 4, stream);

    const int IDXN = Bb * Hh * Cc * Ww;  // 262144
    for (int b0 = 0; b0 < Bb; b0 += bStep) {
        for (int h0 = 0; h0 < Hh; h0 += hStep) {
            k1_gemm<<<dim3(Ll / TL, hStep, bStep), 256, 0, stream>>>(x, means, distT, buckets, lossP, b0, h0);
            k2_topk<<<dim3(Cc, hStep, bStep), 256, 0, stream>>>(distT, out, b0, h0);
        }
    }
    k3_hist<<<1024, 256, 0, stream>>>(buckets, hist);
    k3_scan<<<1, 256, 0, stream>>>(hist, offs, cursor);
    k3_scatter<<<1024, 256, 0, stream>>>(buckets, cursor, sortedTok);
    k3_gather<<<Hh * Cc, 256, 0, stream>>>(x, means, offs, sortedTok, out + IDXN + 1);
    k4_loss<<<1, 256, 0, stream>>>(lossP, out);
}

// Round 4
// 532.780 us; speedup vs baseline: 1.4420x; 1.4420x over previous
//
#include <hip/hip_runtime.h>
#include <hip/hip_bf16.h>

#define Bb 4
#define Hh 8
#define Ll 8192
#define Dd 64
#define Cc 256
#define Ww 32
#define TL 128     // tokens per GEMM block
#define NBLK 64    // Ll / TL
#define CAP 512    // candidate capacity per column

// ---------------- k1: dists GEMM + argmax buckets + loss partials + per-block column-max summary ----------------
// grid (64, 8, 4), block 256. thread tile: 8 tokens x 8 clusters, float4 LDS reads.
// NOTE: no distT write anymore -- replaces 64 MB/launch stream with a 2 MB summary.
__global__ __launch_bounds__(256) void k1_gemm(const float* __restrict__ x,
                                               const float* __restrict__ means,
                                               float* __restrict__ S,
                                               int* __restrict__ buckets,
                                               float* __restrict__ lossP) {
    __shared__ __align__(16) float ms[128 * 68];   // half of means[h] (34 KB)
    __shared__ __align__(16) float xs[TL * 68];    // token tile (34 KB)
    __shared__ float pv[TL * 4];
    __shared__ int   pc[TL * 4];
    __shared__ float msq[256];
    __shared__ float lossAcc;

    const int tid = threadIdx.x;
    const int h   = blockIdx.y, b = blockIdx.z;
    const int l0  = blockIdx.x * TL;
    const int tg  = tid & 15;    // tokens t = tg + 16*jt, jt<8
    const int cg  = tid >> 4;    // clusters c = cg + 16*jl + 128*p, jl<8

    if (tid == 0) lossAcc = 0.f;

    const float* xbase = x + (((size_t)(b * Hh + h)) * Ll + l0) * Dd;
    for (int j = tid; j < TL * 16; j += 256) {
        int t = j >> 4, k4 = (j & 15) << 2;
        *(float4*)&xs[t * 68 + k4] = *(const float4*)(xbase + t * Dd + k4);
    }

    float bvr[8]; int bcr[8];
    #pragma unroll
    for (int jt = 0; jt < 8; jt++) { bvr[jt] = -3.4e38f; bcr[jt] = 0; }

    for (int p = 0; p < 2; p++) {
        __syncthreads();  // covers xs staging (p=0) / protects ms from prev-pass readers (p=1)
        const float* mbase = means + ((size_t)h * Cc + p * 128) * Dd;
        for (int j = tid; j < 128 * 16; j += 256) {
            int r = j >> 4, k4 = (j & 15) << 2;
            *(float4*)&ms[r * 68 + k4] = *(const float4*)(mbase + r * Dd + k4);
        }
        __syncthreads();
        if (tid < 128) {  // |m_c|^2 for the loss
            float s = 0.f;
            #pragma unroll
            for (int k = 0; k < 64; k += 4) {
                float4 m = *(const float4*)&ms[tid * 68 + k];
                s = fmaf(m.x, m.x, s); s = fmaf(m.y, m.y, s);
                s = fmaf(m.z, m.z, s); s = fmaf(m.w, m.w, s);
            }
            msq[(p << 7) + tid] = s;
        }

        float acc[8][8];
        #pragma unroll
        for (int jt = 0; jt < 8; jt++)
            #pragma unroll
            for (int jl = 0; jl < 8; jl++) acc[jt][jl] = 0.f;

        #pragma unroll 4
        for (int k = 0; k < 64; k += 4) {
            float4 xa[8];
            #pragma unroll
            for (int jt = 0; jt < 8; jt++) xa[jt] = *(const float4*)&xs[(tg + 16 * jt) * 68 + k];
            #pragma unroll
            for (int jl = 0; jl < 8; jl++) {
                float4 m = *(const float4*)&ms[(cg + 16 * jl) * 68 + k];
                #pragma unroll
                for (int jt = 0; jt < 8; jt++) {
                    float a = acc[jt][jl];
                    a = fmaf(xa[jt].x, m.x, a); a = fmaf(xa[jt].y, m.y, a);
                    a = fmaf(xa[jt].z, m.z, a); a = fmaf(xa[jt].w, m.w, a);
                    acc[jt][jl] = a;
                }
            }
        }

        // running per-thread argmax (c strictly ascending across jl and p)
        #pragma unroll
        for (int jt = 0; jt < 8; jt++) {
            #pragma unroll
            for (int jl = 0; jl < 8; jl++) {
                int cl = cg + 16 * jl + (p << 7);
                float v = acc[jt][jl];
                if (v > bvr[jt]) { bvr[jt] = v; bcr[jt] = cl; }
            }
        }

        // per-column block-max summary: max over 8 jt in-thread, then over the 16 tg lanes
        #pragma unroll
        for (int jl = 0; jl < 8; jl++) {
            float cm = acc[0][jl];
            #pragma unroll
            for (int jt = 1; jt < 8; jt++) cm = fmaxf(cm, acc[jt][jl]);
            #pragma unroll
            for (int off = 1; off < 16; off <<= 1) cm = fmaxf(cm, __shfl_xor(cm, off));
            if (tg == 0) {
                int cl = cg + 16 * jl + (p << 7);
                S[(((size_t)(b * Hh + h)) * NBLK + blockIdx.x) * Cc + cl] = cm;
            }
        }
    }

    // merge argmax: in-wave across the 4 cluster-groups of this wave, then LDS across waves
    #pragma unroll
    for (int jt = 0; jt < 8; jt++) {
        float bv = bvr[jt]; int bc = bcr[jt];
        #pragma unroll
        for (int off = 16; off <= 32; off <<= 1) {
            float ov = __shfl_xor(bv, off);
            int   oc = __shfl_xor(bc, off);
            if (ov > bv || (ov == bv && oc < bc)) { bv = ov; bc = oc; }
        }
        if ((tid & 48) == 0) { int t = tg + 16 * jt; pv[t * 4 + (tid >> 6)] = bv; pc[t * 4 + (tid >> 6)] = bc; }
    }
    __syncthreads();

    if (tid < TL) {
        int t = tid;
        float bv = pv[t * 4]; int bc = pc[t * 4];
        #pragma unroll
        for (int g = 1; g < 4; g++) {
            float v = pv[t * 4 + g]; int c2 = pc[t * 4 + g];
            if (v > bv || (v == bv && c2 < bc)) { bv = v; bc = c2; }
        }
        float ss = 0.f;
        #pragma unroll
        for (int k = 0; k < 64; k += 4) {
            float4 u = *(const float4*)&xs[t * 68 + k];
            ss = fmaf(u.x, u.x, ss); ss = fmaf(u.y, u.y, ss);
            ss = fmaf(u.z, u.z, ss); ss = fmaf(u.w, u.w, ss);
        }
        buckets[((size_t)(b * Hh + h)) * Ll + l0 + t] = bc;
        atomicAdd(&lossAcc, ss - 2.f * bv + msq[bc]);
    }
    __syncthreads();
    if (tid == 0) lossP[(b * Hh + h) * NBLK + blockIdx.x] = lossAcc;
}

// ---------------- k2t: per-column exact threshold = 32nd-largest of 64 block maxima ----------------
__device__ __forceinline__ unsigned int f2key(float f) {
    unsigned int u = __float_as_uint(f);
    return (u & 0x80000000u) ? ~u : (u | 0x80000000u);
}

// grid 2048, block 256 (4 waves; one column per wave). In-wave bitonic sort of the
// 64 block-maxima; lane 32 of the ascending order = 32nd largest. Since >=32 blocks
// have max >= T (each a DISTINCT token), count(dist >= T) >= 32: exact superset.
__global__ __launch_bounds__(256) void k2_thresh(const float* __restrict__ S,
                                                 unsigned int* __restrict__ Tu) {
    const int tid = threadIdx.x;
    const int lane = tid & 63;
    const int gcol = blockIdx.x * 4 + (tid >> 6);   // ((b*Hh+h)*Cc + c)
    const int bh = gcol >> 8, c = gcol & 255;
    unsigned int key = f2key(S[((size_t)bh * NBLK + lane) * Cc + c]);
    #pragma unroll
    for (int k = 2; k <= 64; k <<= 1) {
        #pragma unroll
        for (int j = k >> 1; j > 0; j >>= 1) {
            unsigned int o = (unsigned int)__shfl_xor((int)key, j);
            bool up = ((lane & k) == 0);
            bool hi = (lane & j) != 0;
            unsigned int mn = key < o ? key : o;
            unsigned int mx = key < o ? o : key;
            key = (up == hi) ? mx : mn;   // ascending region: lower lane takes min
        }
    }
    if (lane == 32) Tu[gcol] = key;       // ascending index 32 == 32nd largest
}

// ---------------- k2c: recompute GEMM (bit-identical) + compact candidates >= T ----------------
// Same grid/tiling/fma order as k1 => bit-identical dists. ~45 hits per column total
// (~0.7 per thread) -> sparse global atomics instead of a 64 MB distT stream.
__global__ __launch_bounds__(256) void k2_cand(const float* __restrict__ x,
                                               const float* __restrict__ means,
                                               const unsigned int* __restrict__ Tu,
                                               unsigned int* __restrict__ colCur,
                                               unsigned int* __restrict__ candK,
                                               int* __restrict__ candI) {
    __shared__ __align__(16) float ms[128 * 68];
    __shared__ __align__(16) float xs[TL * 68];
    __shared__ unsigned int Tl[256];

    const int tid = threadIdx.x;
    const int h   = blockIdx.y, b = blockIdx.z;
    const int l0  = blockIdx.x * TL;
    const int tg  = tid & 15;
    const int cg  = tid >> 4;
    const size_t gbase = ((size_t)(b * Hh + h)) * Cc;

    Tl[tid] = Tu[gbase + tid];

    const float* xbase = x + (((size_t)(b * Hh + h)) * Ll + l0) * Dd;
    for (int j = tid; j < TL * 16; j += 256) {
        int t = j >> 4, k4 = (j & 15) << 2;
        *(float4*)&xs[t * 68 + k4] = *(const float4*)(xbase + t * Dd + k4);
    }

    for (int p = 0; p < 2; p++) {
        __syncthreads();
        const float* mbase = means + ((size_t)h * Cc + p * 128) * Dd;
        for (int j = tid; j < 128 * 16; j += 256) {
            int r = j >> 4, k4 = (j & 15) << 2;
            *(float4*)&ms[r * 68 + k4] = *(const float4*)(mbase + r * Dd + k4);
        }
        __syncthreads();

        float acc[8][8];
        #pragma unroll
        for (int jt = 0; jt < 8; jt++)
            #pragma unroll
            for (int jl = 0; jl < 8; jl++) acc[jt][jl] = 0.f;

        #pragma unroll 4
        for (int k = 0; k < 64; k += 4) {
            float4 xa[8];
            #pragma unroll
            for (int jt = 0; jt < 8; jt++) xa[jt] = *(const float4*)&xs[(tg + 16 * jt) * 68 + k];
            #pragma unroll
            for (int jl = 0; jl < 8; jl++) {
                float4 m = *(const float4*)&ms[(cg + 16 * jl) * 68 + k];
                #pragma unroll
                for (int jt = 0; jt < 8; jt++) {
                    float a = acc[jt][jl];
                    a = fmaf(xa[jt].x, m.x, a); a = fmaf(xa[jt].y, m.y, a);
                    a = fmaf(xa[jt].z, m.z, a); a = fmaf(xa[jt].w, m.w, a);
                    acc[jt][jl] = a;
                }
            }
        }

        #pragma unroll
        for (int jl = 0; jl < 8; jl++) {
            int cl = cg + 16 * jl + (p << 7);
            unsigned int tkey = Tl[cl];
            #pragma unroll
            for (int jt = 0; jt < 8; jt++) {
                unsigned int k = f2key(acc[jt][jl]);
                if (k >= tkey) {
                    unsigned int pos = atomicAdd(&colCur[gbase + cl], 1u);
                    if (pos < CAP) {
                        candK[(gbase + cl) * CAP + pos] = k;
                        candI[(gbase + cl) * CAP + pos] = l0 + tg + 16 * jt;
                    }
                }
            }
        }
    }
}

// ---------------- k3topk: exact stable rank among candidates, output sorted by index ----------------
// grid 2048, block 256 (one column per wave). cnt >= 32 guaranteed; cnt <= CAP always in
// practice (overflow -> exact serial recompute fallback, bit-identical fma order).
__global__ __launch_bounds__(256) void k3_topk(const unsigned int* __restrict__ candK,
                                               const int* __restrict__ candI,
                                               const unsigned int* __restrict__ colCur,
                                               const float* __restrict__ x,
                                               const float* __restrict__ means,
                                               float* __restrict__ outIdx) {
    __shared__ unsigned int sk[4][CAP];
    __shared__ int si[4][CAP];
    __shared__ int comb[4][32];

    const int tid = threadIdx.x;
    const int wv = tid >> 6, lane = tid & 63;
    const int gcol = blockIdx.x * 4 + wv;         // ((b*Hh+h)*Cc + c)
    const int cnt = (int)colCur[gcol];

    if (cnt <= CAP) {
        const unsigned int* ck = candK + (size_t)gcol * CAP;
        const int* ci = candI + (size_t)gcol * CAP;
        for (int i = lane; i < cnt; i += 64) { sk[wv][i] = ck[i]; si[wv][i] = ci[i]; }
        // wave-internal: writes above visible to this wave's later reads (lockstep + waitcnt)
        for (int i = lane; i < cnt; i += 64) {
            unsigned int k = sk[wv][i]; int id = si[wv][i];
            int rk = 0;
            for (int j = 0; j < cnt; j++) {
                unsigned int kj = sk[wv][j];
                rk += (kj > k || (kj == k && si[wv][j] < id)) ? 1 : 0;
            }
            if (rk < 32) comb[wv][rk] = id;
        }
    } else if (lane == 0) {
        // exact fallback: recompute the whole column serially (identical fma order)
        int bh = gcol >> 8, c = gcol & 255;
        int b = bh >> 3, h = bh & 7;
        const float* mc = means + ((size_t)h * Cc + c) * Dd;
        float m[64];
        for (int k = 0; k < 64; k++) m[k] = mc[k];
        unsigned int bk[32]; int bi[32];
        for (int j = 0; j < 32; j++) { bk[j] = 0u; bi[j] = 0; }
        for (int i = 0; i < Ll; i++) {
            const float* xp = x + (((size_t)(b * Hh + h)) * Ll + i) * Dd;
            float d = 0.f;
            for (int k = 0; k < 64; k++) d = fmaf(xp[k], m[k], d);
            unsigned int kk = f2key(d);
            if (kk > bk[31]) {
                int p2 = 31;
                while (p2 > 0 && kk > bk[p2 - 1]) {
                    bk[p2] = bk[p2 - 1]; bi[p2] = bi[p2 - 1]; p2--;
                }
                bk[p2] = kk; bi[p2] = i;
            }
        }
        for (int j = 0; j < 32; j++) comb[wv][j] = bi[j];
    }
    __syncthreads();

    if (lane < Ww) {
        int v = comb[wv][lane];
        int rank = 0;
        #pragma unroll
        for (int j = 0; j < Ww; j++) rank += (comb[wv][j] < v) ? 1 : 0;
        outIdx[(size_t)gcol * Ww + rank] = (float)v;
    }
}

// ---------------- k3: counting sort by (h,cluster), then gather ----------------
__global__ __launch_bounds__(256) void k3_hist(const int* __restrict__ buckets,
                                               unsigned int* __restrict__ hist) {
    __shared__ unsigned int lh[256];
    const int tid = threadIdx.x;
    lh[tid] = 0;
    __syncthreads();
    int i = blockIdx.x * 256 + tid;
    int bk = buckets[i];
    atomicAdd(&lh[bk], 1u);
    __syncthreads();
    int h = (i >> 13) & 7;   // block spans 256 tokens of one (b,h)
    if (lh[tid]) atomicAdd(&hist[h * 256 + tid], lh[tid]);
}

__global__ __launch_bounds__(256) void k3_scan(const unsigned int* __restrict__ hist,
                                               unsigned int* __restrict__ offs,
                                               unsigned int* __restrict__ cursor) {
    __shared__ unsigned int ps[256];
    const int tid = threadIdx.x;
    unsigned int loc[8];
    unsigned s = 0;
    #pragma unroll
    for (int k = 0; k < 8; k++) { loc[k] = hist[tid * 8 + k]; s += loc[k]; }
    ps[tid] = s;
    __syncthreads();
    for (int off = 1; off < 256; off <<= 1) {
        unsigned v = (tid >= off) ? ps[tid - off] : 0;
        __syncthreads();
        ps[tid] += v;
        __syncthreads();
    }
    unsigned base = ps[tid] - s;  // exclusive
    #pragma unroll
    for (int k = 0; k < 8; k++) {
        offs[tid * 8 + k] = base;
        cursor[tid * 8 + k] = base;
        base += loc[k];
    }
    if (tid == 255) offs[2048] = ps[255];
}

__global__ __launch_bounds__(256) void k3_scatter(const int* __restrict__ buckets,
                                                  unsigned int* __restrict__ cursor,
                                                  unsigned int* __restrict__ sortedTok) {
    int i = blockIdx.x * 256 + threadIdx.x;
    int bk = buckets[i];
    int h = (i >> 13) & 7, b = i >> 16, l = i & 8191;
    unsigned pos = atomicAdd(&cursor[h * 256 + bk], 1u);
    sortedTok[pos] = (unsigned)((b << 13) | l);
}

// MLP-restructured gather: lane = (token-slot tl = lane>>4, dim-quad q = lane&15).
__global__ __launch_bounds__(256) void k3_gather(const float* __restrict__ x,
                                                 const float* __restrict__ means,
                                                 const unsigned int* __restrict__ offs,
                                                 const unsigned int* __restrict__ sortedTok,
                                                 float* __restrict__ outMeans) {
    __shared__ __align__(16) float part[4][64];
    const int tid = threadIdx.x;
    const int w = tid >> 6;          // wave 0..3
    const int lane = tid & 63;
    const int tl = lane >> 4;        // token slot within wave 0..3
    const int q  = lane & 15;        // dim quad 0..15 (handles d = 4q..4q+3)
    const int bin = blockIdx.x;
    const int h = bin >> 8, cc = bin & 255;
    const unsigned s0 = offs[bin], s1 = offs[bin + 1];
    const int n = (int)(s1 - s0);

    float4 a0 = make_float4(0.f, 0.f, 0.f, 0.f);
    float4 a1 = make_float4(0.f, 0.f, 0.f, 0.f);
    int j = w * 4 + tl;              // this slot handles j ≡ w*4+tl (mod 16)
    for (; j + 16 < n; j += 32) {    // 2 tokens in flight per slot
        unsigned e0 = sortedTok[s0 + j];
        unsigned e1 = sortedTok[s0 + j + 16];
        const float* p0 = x + (((size_t)((int)(e0 >> 13) * Hh + h)) * Ll + (e0 & 8191)) * Dd + q * 4;
        const float* p1 = x + (((size_t)((int)(e1 >> 13) * Hh + h)) * Ll + (e1 & 8191)) * Dd + q * 4;
        float4 v0 = *(const float4*)p0;
        float4 v1 = *(const float4*)p1;
        a0.x += v0.x; a0.y += v0.y; a0.z += v0.z; a0.w += v0.w;
        a1.x += v1.x; a1.y += v1.y; a1.z += v1.z; a1.w += v1.w;
    }
    for (; j < n; j += 16) {         // at most one leftover token per slot
        unsigned e = sortedTok[s0 + j];
        const float* p = x + (((size_t)((int)(e >> 13) * Hh + h)) * Ll + (e & 8191)) * Dd + q * 4;
        float4 v = *(const float4*)p;
        a0.x += v.x; a0.y += v.y; a0.z += v.z; a0.w += v.w;
    }
    a0.x += a1.x; a0.y += a1.y; a0.z += a1.z; a0.w += a1.w;

    // reduce across the 4 token slots (lane bits 4 and 5)
    #pragma unroll
    for (int off = 16; off <= 32; off <<= 1) {
        a0.x += __shfl_xor(a0.x, off);
        a0.y += __shfl_xor(a0.y, off);
        a0.z += __shfl_xor(a0.z, off);
        a0.w += __shfl_xor(a0.w, off);
    }
    if (tl == 0) *(float4*)&part[w][q * 4] = a0;
    __syncthreads();

    if (tid < 64) {
        const int d = tid;
        float s = part[0][d] + part[1][d] + part[2][d] + part[3][d];
        float t = s * s;
        #pragma unroll
        for (int off = 32; off; off >>= 1) t += __shfl_xor(t, off);
        float nrm = sqrtf(t);
        float outv = (n == 0) ? means[((size_t)(h * Cc + cc)) * Dd + d]
                              : s / fmaxf(nrm, 1e-12f);
        outMeans[((size_t)(h * Cc + cc)) * Dd + d] = outv;
    }
}

// ---------------- k4: loss reduction ----------------
__global__ __launch_bounds__(256) void k4_loss(const float* __restrict__ lossP,
                                               float* __restrict__ out) {
    __shared__ float red[256];
    const int tid = threadIdx.x;
    float s = 0.f;
    for (int i = tid; i < Bb * Hh * NBLK; i += 256) s += lossP[i];
    red[tid] = s;
    __syncthreads();
    for (int off = 128; off; off >>= 1) {
        if (tid < off) red[tid] += red[tid + off];
        __syncthreads();
    }
    if (tid == 0)
        out[(size_t)Bb * Hh * Cc * Ww] = red[0] * (1e-4f / (float)((size_t)Bb * Hh * Ll * Dd));
}

extern "C" void kernel_launch(void* const* d_in, const int* in_sizes, int n_in,
                              void* d_out, int out_size, void* d_ws, size_t ws_size,
                              hipStream_t stream) {
    (void)in_sizes; (void)n_in; (void)out_size; (void)ws_size;
    const float* x = (const float*)d_in[0];
    const float* means = (const float*)d_in[1];
    float* out = (float*)d_out;

    char* ws = (char*)d_ws;
    float* lossP = (float*)ws;                               // 2048 f (8 KB)
    int* buckets = (int*)(ws + 8192);                        // 1 MB
    unsigned int* hist = (unsigned int*)(ws + 8192 + 1048576);   // 2048 u
    unsigned int* offs = hist + 2048;                        // 2049 u
    unsigned int* cursor = offs + 2049;                      // 2048 u
    unsigned int* sortedTok = cursor + 2048;                 // 262144 u (1 MB)
    size_t base = 8192 + 1048576 + 4ull * (2048 + 2049 + 2048) + 4ull * 262144;
    base = (base + 255) & ~255ull;
    float* S = (float*)(ws + base);                          // 4*8*64*256 f = 2 MB
    unsigned int* Tu = (unsigned int*)(S + (size_t)Bb * Hh * NBLK * Cc);  // 8192 u
    unsigned int* colCur = Tu + Bb * Hh * Cc;                // 8192 u
    unsigned int* candK = colCur + Bb * Hh * Cc;             // 8192*CAP u = 16 MB
    int* candI = (int*)(candK + (size_t)Bb * Hh * Cc * CAP); // 16 MB
    // total ~36.5 MB (ws known >= ~66 MB from prior distT layout fitting)

    hipMemsetAsync(hist, 0, 2048 * 4, stream);
    hipMemsetAsync(colCur, 0, Bb * Hh * Cc * 4, stream);

    const int IDXN = Bb * Hh * Cc * Ww;  // 262144

    k1_gemm<<<dim3(NBLK, Hh, Bb), 256, 0, stream>>>(x, means, S, buckets, lossP);
    k2_thresh<<<Bb * Hh * Cc / 4, 256, 0, stream>>>(S, Tu);
    k2_cand<<<dim3(NBLK, Hh, Bb), 256, 0, stream>>>(x, means, Tu, colCur, candK, candI);
    k3_topk<<<Bb * Hh * Cc / 4, 256, 0, stream>>>(candK, candI, colCur, x, means, out);
    k3_hist<<<1024, 256, 0, stream>>>(buckets, hist);
    k3_scan<<<1, 256, 0, stream>>>(hist, offs, cursor);
    k3_scatter<<<1024, 256, 0, stream>>>(buckets, cursor, sortedTok);
    k3_gather<<<Hh * Cc, 256, 0, stream>>>(x, means, offs, sortedTok, out + IDXN + 1);
    k4_loss<<<1, 256, 0, stream>>>(lossP, out);
}

// Round 5
// 464.431 us; speedup vs baseline: 1.6543x; 1.1472x over previous
//
#include <hip/hip_runtime.h>
#include <hip/hip_bf16.h>

#define Bb 4
#define Hh 8
#define Ll 8192
#define Dd 64
#define Cc 256
#define Ww 32
#define TL 128     // tokens per k1 block
#define NBLK 64    // Ll / TL
#define CAP2 2048  // k2_sel LDS candidate capacity (expected cnt ~45)

// ---------------- k1: dists GEMM + argmax buckets + loss partials + dist_T + tile-max summary ----------------
// grid (Ll/TL, hStep, bStep), block 256. thread tile: 8 tokens x 8 clusters, float4 LDS reads.
__global__ __launch_bounds__(256) void k1_gemm(const float* __restrict__ x,
                                               const float* __restrict__ means,
                                               float* __restrict__ distT,
                                               float* __restrict__ S,
                                               int* __restrict__ buckets,
                                               float* __restrict__ lossP,
                                               int b0, int h0) {
    __shared__ __align__(16) float ms[128 * 68];   // half of means[h] (34 KB)
    __shared__ __align__(16) float xs[TL * 68];    // token tile (34 KB)
    __shared__ float pv[TL * 4];
    __shared__ int   pc[TL * 4];
    __shared__ float msq[256];
    __shared__ float lossAcc;

    const int tid = threadIdx.x;
    const int hl  = blockIdx.y, bz = blockIdx.z;
    const int h   = h0 + hl,    b  = b0 + bz;
    const int l0  = blockIdx.x * TL;
    const int tg  = tid & 15;    // tokens t = tg + 16*jt, jt<8
    const int cg  = tid >> 4;    // clusters c = cg + 16*jl + 128*p, jl<8

    if (tid == 0) lossAcc = 0.f;

    const float* xbase = x + (((size_t)(b * Hh + h)) * Ll + l0) * Dd;
    for (int j = tid; j < TL * 16; j += 256) {
        int t = j >> 4, k4 = (j & 15) << 2;
        *(float4*)&xs[t * 68 + k4] = *(const float4*)(xbase + t * Dd + k4);
    }

    float bvr[8]; int bcr[8];
    #pragma unroll
    for (int jt = 0; jt < 8; jt++) { bvr[jt] = -3.4e38f; bcr[jt] = 0; }

    const size_t pbase = ((size_t)(bz * gridDim.y + hl)) * Cc;   // pass-local plane * Cc

    for (int p = 0; p < 2; p++) {
        __syncthreads();  // covers xs staging (p=0) / protects ms from prev-pass readers (p=1)
        const float* mbase = means + ((size_t)h * Cc + p * 128) * Dd;
        for (int j = tid; j < 128 * 16; j += 256) {
            int r = j >> 4, k4 = (j & 15) << 2;
            *(float4*)&ms[r * 68 + k4] = *(const float4*)(mbase + r * Dd + k4);
        }
        __syncthreads();
        if (tid < 128) {  // |m_c|^2 for the loss
            float s = 0.f;
            #pragma unroll
            for (int k = 0; k < 64; k += 4) {
                float4 m = *(const float4*)&ms[tid * 68 + k];
                s = fmaf(m.x, m.x, s); s = fmaf(m.y, m.y, s);
                s = fmaf(m.z, m.z, s); s = fmaf(m.w, m.w, s);
            }
            msq[(p << 7) + tid] = s;
        }

        float acc[8][8];
        #pragma unroll
        for (int jt = 0; jt < 8; jt++)
            #pragma unroll
            for (int jl = 0; jl < 8; jl++) acc[jt][jl] = 0.f;

        #pragma unroll 4
        for (int k = 0; k < 64; k += 4) {
            float4 xa[8];
            #pragma unroll
            for (int jt = 0; jt < 8; jt++) xa[jt] = *(const float4*)&xs[(tg + 16 * jt) * 68 + k];
            #pragma unroll
            for (int jl = 0; jl < 8; jl++) {
                float4 m = *(const float4*)&ms[(cg + 16 * jl) * 68 + k];
                #pragma unroll
                for (int jt = 0; jt < 8; jt++) {
                    float a = acc[jt][jl];
                    a = fmaf(xa[jt].x, m.x, a); a = fmaf(xa[jt].y, m.y, a);
                    a = fmaf(xa[jt].z, m.z, a); a = fmaf(xa[jt].w, m.w, a);
                    acc[jt][jl] = a;
                }
            }
        }

        // dist_T writes + running per-thread argmax (c strictly ascending across jl and p)
        #pragma unroll
        for (int jt = 0; jt < 8; jt++) {
            int t = tg + 16 * jt;
            #pragma unroll
            for (int jl = 0; jl < 8; jl++) {
                int cl = cg + 16 * jl + (p << 7);
                float v = acc[jt][jl];
                distT[(pbase + cl) * Ll + l0 + t] = v;
                if (v > bvr[jt]) { bvr[jt] = v; bcr[jt] = cl; }
            }
        }

        // per-column tile-max summary (verified exact in round 4)
        #pragma unroll
        for (int jl = 0; jl < 8; jl++) {
            float cm = acc[0][jl];
            #pragma unroll
            for (int jt = 1; jt < 8; jt++) cm = fmaxf(cm, acc[jt][jl]);
            #pragma unroll
            for (int off = 1; off < 16; off <<= 1) cm = fmaxf(cm, __shfl_xor(cm, off));
            if (tg == 0) {
                int cl = cg + 16 * jl + (p << 7);
                S[(((size_t)(bz * gridDim.y + hl)) * NBLK + blockIdx.x) * Cc + cl] = cm;
            }
        }
    }

    // merge argmax: in-wave across the 4 cluster-groups of this wave, then LDS across waves
    #pragma unroll
    for (int jt = 0; jt < 8; jt++) {
        float bv = bvr[jt]; int bc = bcr[jt];
        #pragma unroll
        for (int off = 16; off <= 32; off <<= 1) {
            float ov = __shfl_xor(bv, off);
            int   oc = __shfl_xor(bc, off);
            if (ov > bv || (ov == bv && oc < bc)) { bv = ov; bc = oc; }
        }
        if ((tid & 48) == 0) { int t = tg + 16 * jt; pv[t * 4 + (tid >> 6)] = bv; pc[t * 4 + (tid >> 6)] = bc; }
    }
    __syncthreads();

    if (tid < TL) {
        int t = tid;
        float bv = pv[t * 4]; int bc = pc[t * 4];
        #pragma unroll
        for (int g = 1; g < 4; g++) {
            float v = pv[t * 4 + g]; int c2 = pc[t * 4 + g];
            if (v > bv || (v == bv && c2 < bc)) { bv = v; bc = c2; }
        }
        float ss = 0.f;
        #pragma unroll
        for (int k = 0; k < 64; k += 4) {
            float4 u = *(const float4*)&xs[t * 68 + k];
            ss = fmaf(u.x, u.x, ss); ss = fmaf(u.y, u.y, ss);
            ss = fmaf(u.z, u.z, ss); ss = fmaf(u.w, u.w, ss);
        }
        buckets[((size_t)(b * Hh + h)) * Ll + l0 + t] = bc;
        atomicAdd(&lossAcc, ss - 2.f * bv + msq[bc]);
    }
    __syncthreads();
    if (tid == 0) lossP[(b * Hh + h) * (Ll / TL) + blockIdx.x] = lossAcc;
}

// ---------------- k2t: per-column exact threshold = 32nd-largest of 64 tile maxima ----------------
__device__ __forceinline__ unsigned int f2key(float f) {
    unsigned int u = __float_as_uint(f);
    return (u & 0x80000000u) ? ~u : (u | 0x80000000u);
}

// block 256 (4 waves; one pass-local column per wave). In-wave bitonic sort of the 64
// tile maxima; ascending lane 32 == 32nd largest. >=32 distinct tokens have dist >= T
// => count(dist >= T) >= 32 => top-32 subset of {dist >= T}. (field-verified round 4)
__global__ __launch_bounds__(256) void k2_thresh(const float* __restrict__ S,
                                                 unsigned int* __restrict__ Tu) {
    const int tid = threadIdx.x;
    const int lane = tid & 63;
    const int gcol = blockIdx.x * 4 + (tid >> 6);   // pass-local (plane*Cc + c)
    const int pl = gcol >> 8, c = gcol & 255;
    unsigned int key = f2key(S[((size_t)pl * NBLK + lane) * Cc + c]);
    #pragma unroll
    for (int k = 2; k <= 64; k <<= 1) {
        #pragma unroll
        for (int j = k >> 1; j > 0; j >>= 1) {
            unsigned int o = (unsigned int)__shfl_xor((int)key, j);
            bool up = ((lane & k) == 0);
            bool hi = (lane & j) != 0;
            unsigned int mn = key < o ? key : o;
            unsigned int mx = key < o ? o : key;
            key = (up == hi) ? mx : mn;
        }
    }
    if (lane == 32) Tu[gcol] = key;
}

// ---------------- k2_sel: stream column, compact >= T, exact stable rank, sorted-index output ----------------
// grid (Cc, hStep, bStep), block 256. Pure float4 stream + ~45 LDS pushes + tiny rank loop.
// Replaces radix (LDS hot-bin atomics, r1), sample-rank (256-iter LDS loop, r2),
// ballot-search (barrier-in-loop, r3) -- all of which were selection-overhead bound.
__global__ __launch_bounds__(256) void k2_sel(const float* __restrict__ distT,
                                              const unsigned int* __restrict__ Tu,
                                              float* __restrict__ outIdx,
                                              int b0, int h0) {
    __shared__ unsigned int sCnt;
    __shared__ unsigned int candK[CAP2];
    __shared__ int candI[CAP2];
    __shared__ int comb[32];

    const int tid = threadIdx.x;
    const int c = blockIdx.x, hl = blockIdx.y, bz = blockIdx.z;
    const int h = h0 + hl, b = b0 + bz;
    const int pcol = (bz * gridDim.y + hl) * Cc + c;      // pass-local column
    const float* col = distT + (size_t)pcol * Ll;
    const unsigned int T = Tu[pcol];

    if (tid == 0) sCnt = 0u;
    __syncthreads();

    #pragma unroll
    for (int j = 0; j < 8; j++) {
        float4 v = *(const float4*)(col + j * 1024 + tid * 4);
        unsigned int kk0 = f2key(v.x), kk1 = f2key(v.y), kk2 = f2key(v.z), kk3 = f2key(v.w);
        int ib = j * 1024 + tid * 4;
        if (kk0 >= T) { unsigned p = atomicAdd(&sCnt, 1u); if (p < CAP2) { candK[p] = kk0; candI[p] = ib; } }
        if (kk1 >= T) { unsigned p = atomicAdd(&sCnt, 1u); if (p < CAP2) { candK[p] = kk1; candI[p] = ib + 1; } }
        if (kk2 >= T) { unsigned p = atomicAdd(&sCnt, 1u); if (p < CAP2) { candK[p] = kk2; candI[p] = ib + 2; } }
        if (kk3 >= T) { unsigned p = atomicAdd(&sCnt, 1u); if (p < CAP2) { candK[p] = kk3; candI[p] = ib + 3; } }
    }
    __syncthreads();
    const int cnt = (int)sCnt;

    if (cnt <= CAP2) {
        // exact stable rank among candidates (== global rank for all top-32 elements)
        for (int i = tid; i < cnt; i += 256) {
            unsigned int k = candK[i]; int id = candI[i];
            int rk = 0;
            for (int j2 = 0; j2 < cnt; j2++) {
                unsigned int kj = candK[j2];
                rk += (kj > k || (kj == k && candI[j2] < id)) ? 1 : 0;
            }
            if (rk < 32) comb[rk] = id;
        }
        __syncthreads();
    } else {
        // pathological tie flood: exact serial stable top-32 from the column
        if (tid == 0) {
            unsigned int bk[32]; int bi[32];
            for (int j = 0; j < 32; j++) { bk[j] = 0u; bi[j] = 0; }
            for (int i = 0; i < Ll; i++) {
                unsigned int kk = f2key(col[i]);
                if (kk > bk[31]) {
                    int p2 = 31;
                    while (p2 > 0 && kk > bk[p2 - 1]) {
                        bk[p2] = bk[p2 - 1]; bi[p2] = bi[p2 - 1]; p2--;
                    }
                    bk[p2] = kk; bi[p2] = i;
                }
            }
            for (int j = 0; j < 32; j++) comb[j] = bi[j];
        }
        __syncthreads();
    }

    if (tid < Ww) {
        int v = comb[tid];
        int rank = 0;
        #pragma unroll
        for (int j = 0; j < Ww; j++) rank += (comb[j] < v);
        outIdx[(((size_t)(b * Hh + h)) * Cc + c) * Ww + rank] = (float)v;
    }
}

// ---------------- k3: counting sort by (h,cluster), then gather ----------------
__global__ __launch_bounds__(256) void k3_hist(const int* __restrict__ buckets,
                                               unsigned int* __restrict__ hist) {
    __shared__ unsigned int lh[256];
    const int tid = threadIdx.x;
    lh[tid] = 0;
    __syncthreads();
    int i = blockIdx.x * 256 + tid;
    int bk = buckets[i];
    atomicAdd(&lh[bk], 1u);
    __syncthreads();
    int h = (i >> 13) & 7;   // block spans 256 tokens of one (b,h)
    if (lh[tid]) atomicAdd(&hist[h * 256 + tid], lh[tid]);
}

__global__ __launch_bounds__(256) void k3_scan(const unsigned int* __restrict__ hist,
                                               unsigned int* __restrict__ offs,
                                               unsigned int* __restrict__ cursor) {
    __shared__ unsigned int ps[256];
    const int tid = threadIdx.x;
    unsigned int loc[8];
    unsigned s = 0;
    #pragma unroll
    for (int k = 0; k < 8; k++) { loc[k] = hist[tid * 8 + k]; s += loc[k]; }
    ps[tid] = s;
    __syncthreads();
    for (int off = 1; off < 256; off <<= 1) {
        unsigned v = (tid >= off) ? ps[tid - off] : 0;
        __syncthreads();
        ps[tid] += v;
        __syncthreads();
    }
    unsigned base = ps[tid] - s;  // exclusive
    #pragma unroll
    for (int k = 0; k < 8; k++) {
        offs[tid * 8 + k] = base;
        cursor[tid * 8 + k] = base;
        base += loc[k];
    }
    if (tid == 255) offs[2048] = ps[255];
}

__global__ __launch_bounds__(256) void k3_scatter(const int* __restrict__ buckets,
                                                  unsigned int* __restrict__ cursor,
                                                  unsigned int* __restrict__ sortedTok) {
    int i = blockIdx.x * 256 + threadIdx.x;
    int bk = buckets[i];
    int h = (i >> 13) & 7, b = i >> 16, l = i & 8191;
    unsigned pos = atomicAdd(&cursor[h * 256 + bk], 1u);
    sortedTok[pos] = (unsigned)((b << 13) | l);
}

// MLP-restructured gather: lane = (token-slot tl = lane>>4, dim-quad q = lane&15).
__global__ __launch_bounds__(256) void k3_gather(const float* __restrict__ x,
                                                 const float* __restrict__ means,
                                                 const unsigned int* __restrict__ offs,
                                                 const unsigned int* __restrict__ sortedTok,
                                                 float* __restrict__ outMeans) {
    __shared__ __align__(16) float part[4][64];
    const int tid = threadIdx.x;
    const int w = tid >> 6;          // wave 0..3
    const int lane = tid & 63;
    const int tl = lane >> 4;        // token slot within wave 0..3
    const int q  = lane & 15;        // dim quad 0..15 (handles d = 4q..4q+3)
    const int bin = blockIdx.x;
    const int h = bin >> 8, cc = bin & 255;
    const unsigned s0 = offs[bin], s1 = offs[bin + 1];
    const int n = (int)(s1 - s0);

    float4 a0 = make_float4(0.f, 0.f, 0.f, 0.f);
    float4 a1 = make_float4(0.f, 0.f, 0.f, 0.f);
    int j = w * 4 + tl;              // this slot handles j ≡ w*4+tl (mod 16)
    for (; j + 16 < n; j += 32) {    // 2 tokens in flight per slot
        unsigned e0 = sortedTok[s0 + j];
        unsigned e1 = sortedTok[s0 + j + 16];
        const float* p0 = x + (((size_t)((int)(e0 >> 13) * Hh + h)) * Ll + (e0 & 8191)) * Dd + q * 4;
        const float* p1 = x + (((size_t)((int)(e1 >> 13) * Hh + h)) * Ll + (e1 & 8191)) * Dd + q * 4;
        float4 v0 = *(const float4*)p0;
        float4 v1 = *(const float4*)p1;
        a0.x += v0.x; a0.y += v0.y; a0.z += v0.z; a0.w += v0.w;
        a1.x += v1.x; a1.y += v1.y; a1.z += v1.z; a1.w += v1.w;
    }
    for (; j < n; j += 16) {         // at most one leftover token per slot
        unsigned e = sortedTok[s0 + j];
        const float* p = x + (((size_t)((int)(e >> 13) * Hh + h)) * Ll + (e & 8191)) * Dd + q * 4;
        float4 v = *(const float4*)p;
        a0.x += v.x; a0.y += v.y; a0.z += v.z; a0.w += v.w;
    }
    a0.x += a1.x; a0.y += a1.y; a0.z += a1.z; a0.w += a1.w;

    // reduce across the 4 token slots (lane bits 4 and 5)
    #pragma unroll
    for (int off = 16; off <= 32; off <<= 1) {
        a0.x += __shfl_xor(a0.x, off);
        a0.y += __shfl_xor(a0.y, off);
        a0.z += __shfl_xor(a0.z, off);
        a0.w += __shfl_xor(a0.w, off);
    }
    if (tl == 0) *(float4*)&part[w][q * 4] = a0;
    __syncthreads();

    if (tid < 64) {
        const int d = tid;
        float s = part[0][d] + part[1][d] + part[2][d] + part[3][d];
        float t = s * s;
        #pragma unroll
        for (int off = 32; off; off >>= 1) t += __shfl_xor(t, off);
        float nrm = sqrtf(t);
        float outv = (n == 0) ? means[((size_t)(h * Cc + cc)) * Dd + d]
                              : s / fmaxf(nrm, 1e-12f);
        outMeans[((size_t)(h * Cc + cc)) * Dd + d] = outv;
    }
}

// ---------------- k4: loss reduction ----------------
__global__ __launch_bounds__(256) void k4_loss(const float* __restrict__ lossP,
                                               float* __restrict__ out) {
    __shared__ float red[256];
    const int tid = threadIdx.x;
    float s = 0.f;
    for (int i = tid; i < Bb * Hh * (Ll / TL); i += 256) s += lossP[i];
    red[tid] = s;
    __syncthreads();
    for (int off = 128; off; off >>= 1) {
        if (tid < off) red[tid] += red[tid + off];
        __syncthreads();
    }
    if (tid == 0)
        out[(size_t)Bb * Hh * Cc * Ww] = red[0] * (1e-4f / (float)((size_t)Bb * Hh * Ll * Dd));
}

extern "C" void kernel_launch(void* const* d_in, const int* in_sizes, int n_in,
                              void* d_out, int out_size, void* d_ws, size_t ws_size,
                              hipStream_t stream) {
    (void)in_sizes; (void)n_in; (void)out_size;
    const float* x = (const float*)d_in[0];
    const float* means = (const float*)d_in[1];
    float* out = (float*)d_out;

    char* ws = (char*)d_ws;
    float* lossP = (float*)ws;                              // 2048 floats (8 KB)
    int* buckets = (int*)(ws + 8192);                       // 1 MB
    unsigned int* hist = (unsigned int*)(ws + 8192 + 1048576);       // 2048
    unsigned int* offs = hist + 2048;                       // 2049
    unsigned int* cursor = offs + 2049;                     // 2048
    unsigned int* sortedTok = cursor + 2048;                // 262144 (1 MB)
    size_t base = 8192 + 1048576 + 4ull * (2048 + 2049 + 2048) + 4ull * 262144;
    base = (base + 255) & ~255ull;
    // fixed-size S (max 32 planes) + Tu, then variable-size distT
    float* S = (float*)(ws + base);                         // 32*64*256 f = 2 MB (max)
    unsigned int* Tu = (unsigned int*)(S + (size_t)32 * NBLK * Cc);  // 8192 u (max)
    size_t dbase = base + 4ull * 32 * NBLK * Cc + 4ull * 32 * Cc;
    dbase = (dbase + 255) & ~255ull;
    float* distT = (float*)(ws + dbase);
    const size_t perPlane = (size_t)Cc * Ll * 4;            // 8 MB per (b,h) plane

    int bStep = 4, hStep = 8;
    if (dbase + (size_t)bStep * hStep * perPlane > ws_size) bStep = 1;
    while (hStep > 1 && dbase + (size_t)bStep * hStep * perPlane > ws_size) hStep >>= 1;

    hipMemsetAsync(hist, 0, 2048 * 4, stream);

    const int IDXN = Bb * Hh * Cc * Ww;  // 262144
    for (int b0 = 0; b0 < Bb; b0 += bStep) {
        for (int h0 = 0; h0 < Hh; h0 += hStep) {
            k1_gemm<<<dim3(Ll / TL, hStep, bStep), 256, 0, stream>>>(x, means, distT, S, buckets, lossP, b0, h0);
            k2_thresh<<<bStep * hStep * Cc / 4, 256, 0, stream>>>(S, Tu);
            k2_sel<<<dim3(Cc, hStep, bStep), 256, 0, stream>>>(distT, Tu, out, b0, h0);
        }
    }
    k3_hist<<<1024, 256, 0, stream>>>(buckets, hist);
    k3_scan<<<1, 256, 0, stream>>>(hist, offs, cursor);
    k3_scatter<<<1024, 256, 0, stream>>>(buckets, cursor, sortedTok);
    k3_gather<<<Hh * Cc, 256, 0, stream>>>(x, means, offs, sortedTok, out + IDXN + 1);
    k4_loss<<<1, 256, 0, stream>>>(lossP, out);
}

// Round 6
// 457.690 us; speedup vs baseline: 1.6786x; 1.0147x over previous
//
#include <hip/hip_runtime.h>
#include <hip/hip_bf16.h>

#define Bb 4
#define Hh 8
#define Ll 8192
#define Dd 64
#define Cc 256
#define Ww 32
#define TL 64      // tokens per k1 block (was 128): halves xs
#define CLP 64     // clusters per pass (was 128): halves ms; 4 passes
#define NBLK 128   // Ll / TL tiles per plane
#define CAP2 2048  // k2_sel LDS candidate capacity

// ---------------- k1: dists GEMM + argmax buckets + loss partials + dist_T + tile-max summary ----------------
// grid (Ll/TL, hStep, bStep), block 256, __launch_bounds__(256,4).
// LDS ~38 KB -> 4 blocks/CU (16 waves/CU, 4/SIMD) vs old 75 KB -> 2 blocks/CU.
// thread tile: 4 tokens x 4 clusters x 4 passes; FMA:LDS-issue per k-step = 64:8.
__global__ __launch_bounds__(256, 4) void k1_gemm(const float* __restrict__ x,
                                                  const float* __restrict__ means,
                                                  float* __restrict__ distT,
                                                  float* __restrict__ S,
                                                  int* __restrict__ buckets,
                                                  float* __restrict__ lossP,
                                                  int b0, int h0) {
    __shared__ __align__(16) float ms[CLP * 68];   // 17.4 KB
    __shared__ __align__(16) float xs[TL * 68];    // 17.4 KB
    __shared__ float pv[TL * 4];
    __shared__ int   pc[TL * 4];
    __shared__ float msq[256];
    __shared__ float lossAcc;

    const int tid = threadIdx.x;
    const int hl  = blockIdx.y, bz = blockIdx.z;
    const int h   = h0 + hl,    b  = b0 + bz;
    const int l0  = blockIdx.x * TL;
    const int tg  = tid & 15;    // tokens t = tg + 16*jt, jt<4
    const int cg  = tid >> 4;    // clusters c = cg + 16*jl + CLP*p, jl<4

    if (tid == 0) lossAcc = 0.f;

    const float* xbase = x + (((size_t)(b * Hh + h)) * Ll + l0) * Dd;
    for (int j = tid; j < TL * 16; j += 256) {      // 4 iters
        int t = j >> 4, k4 = (j & 15) << 2;
        *(float4*)&xs[t * 68 + k4] = *(const float4*)(xbase + t * Dd + k4);
    }

    float bvr[4]; int bcr[4];
    #pragma unroll
    for (int jt = 0; jt < 4; jt++) { bvr[jt] = -3.4e38f; bcr[jt] = 0; }

    const size_t pbase = ((size_t)(bz * gridDim.y + hl)) * Cc;   // pass-local plane * Cc
    const size_t srow  = (((size_t)(bz * gridDim.y + hl)) * NBLK + blockIdx.x) * Cc;

    for (int p = 0; p < 4; p++) {
        __syncthreads();  // covers xs staging (p=0) / protects ms from prev-pass readers
        const float* mbase = means + ((size_t)h * Cc + p * CLP) * Dd;
        for (int j = tid; j < CLP * 16; j += 256) { // 4 iters
            int r = j >> 4, k4 = (j & 15) << 2;
            *(float4*)&ms[r * 68 + k4] = *(const float4*)(mbase + r * Dd + k4);
        }
        __syncthreads();
        if (tid < CLP) {  // |m_c|^2 for the loss
            float s = 0.f;
            #pragma unroll
            for (int k = 0; k < 64; k += 4) {
                float4 m = *(const float4*)&ms[tid * 68 + k];
                s = fmaf(m.x, m.x, s); s = fmaf(m.y, m.y, s);
                s = fmaf(m.z, m.z, s); s = fmaf(m.w, m.w, s);
            }
            msq[p * CLP + tid] = s;
        }

        float acc[4][4];
        #pragma unroll
        for (int jt = 0; jt < 4; jt++)
            #pragma unroll
            for (int jl = 0; jl < 4; jl++) acc[jt][jl] = 0.f;

        #pragma unroll 4
        for (int k = 0; k < 64; k += 4) {
            float4 xa[4];
            #pragma unroll
            for (int jt = 0; jt < 4; jt++) xa[jt] = *(const float4*)&xs[(tg + 16 * jt) * 68 + k];
            #pragma unroll
            for (int jl = 0; jl < 4; jl++) {
                float4 m = *(const float4*)&ms[(cg + 16 * jl) * 68 + k];
                #pragma unroll
                for (int jt = 0; jt < 4; jt++) {
                    float a = acc[jt][jl];
                    a = fmaf(xa[jt].x, m.x, a); a = fmaf(xa[jt].y, m.y, a);
                    a = fmaf(xa[jt].z, m.z, a); a = fmaf(xa[jt].w, m.w, a);
                    acc[jt][jl] = a;
                }
            }
        }

        // dist_T writes + running per-thread argmax (cl strictly ascending across jl and p)
        #pragma unroll
        for (int jt = 0; jt < 4; jt++) {
            int t = tg + 16 * jt;
            #pragma unroll
            for (int jl = 0; jl < 4; jl++) {
                int cl = cg + 16 * jl + p * CLP;
                float v = acc[jt][jl];
                distT[(pbase + cl) * Ll + l0 + t] = v;
                if (v > bvr[jt]) { bvr[jt] = v; bcr[jt] = cl; }
            }
        }

        // per-column tile-max summary (threshold machinery field-verified r4/r5)
        #pragma unroll
        for (int jl = 0; jl < 4; jl++) {
            float cm = acc[0][jl];
            #pragma unroll
            for (int jt = 1; jt < 4; jt++) cm = fmaxf(cm, acc[jt][jl]);
            #pragma unroll
            for (int off = 1; off < 16; off <<= 1) cm = fmaxf(cm, __shfl_xor(cm, off));
            if (tg == 0) S[srow + cg + 16 * jl + p * CLP] = cm;
        }
    }

    // merge argmax: in-wave across the 4 cluster-groups of this wave, then LDS across waves
    #pragma unroll
    for (int jt = 0; jt < 4; jt++) {
        float bv = bvr[jt]; int bc = bcr[jt];
        #pragma unroll
        for (int off = 16; off <= 32; off <<= 1) {
            float ov = __shfl_xor(bv, off);
            int   oc = __shfl_xor(bc, off);
            if (ov > bv || (ov == bv && oc < bc)) { bv = ov; bc = oc; }
        }
        if ((tid & 48) == 0) { int t = tg + 16 * jt; pv[t * 4 + (tid >> 6)] = bv; pc[t * 4 + (tid >> 6)] = bc; }
    }
    __syncthreads();

    if (tid < TL) {
        int t = tid;
        float bv = pv[t * 4]; int bc = pc[t * 4];
        #pragma unroll
        for (int g = 1; g < 4; g++) {
            float v = pv[t * 4 + g]; int c2 = pc[t * 4 + g];
            if (v > bv || (v == bv && c2 < bc)) { bv = v; bc = c2; }
        }
        float ss = 0.f;
        #pragma unroll
        for (int k = 0; k < 64; k += 4) {
            float4 u = *(const float4*)&xs[t * 68 + k];
            ss = fmaf(u.x, u.x, ss); ss = fmaf(u.y, u.y, ss);
            ss = fmaf(u.z, u.z, ss); ss = fmaf(u.w, u.w, ss);
        }
        buckets[((size_t)(b * Hh + h)) * Ll + l0 + t] = bc;
        atomicAdd(&lossAcc, ss - 2.f * bv + msq[bc]);
    }
    __syncthreads();
    if (tid == 0) lossP[(b * Hh + h) * NBLK + blockIdx.x] = lossAcc;
}

// ---------------- k2_sel: fused threshold + stream-compact + exact stable rank ----------------
__device__ __forceinline__ unsigned int f2key(float f) {
    unsigned int u = __float_as_uint(f);
    return (u & 0x80000000u) ? ~u : (u | 0x80000000u);
}

// grid (Cc, hStep, bStep), block 256. Wave 0 computes T inline (bitonic-64 of super-tile
// maxima, = round-5's k2_thresh) while all threads' key loads are in flight.
// T = 32nd-largest of 64 disjoint 128-token super-tile maxima => >=32 distinct tokens
// have key >= T => top-32 subset of candidates; rank-in-candidates == global rank. Exact.
__global__ __launch_bounds__(256) void k2_sel(const float* __restrict__ distT,
                                              const float* __restrict__ S,
                                              float* __restrict__ outIdx,
                                              int b0, int h0) {
    __shared__ unsigned int sT, sCnt;
    __shared__ unsigned int candK[CAP2];
    __shared__ int candI[CAP2];
    __shared__ int comb[32];

    const int tid = threadIdx.x;
    const int c = blockIdx.x, hl = blockIdx.y, bz = blockIdx.z;
    const int h = h0 + hl, b = b0 + bz;
    const int pl = bz * gridDim.y + hl;                   // pass-local plane
    const float* col = distT + ((size_t)pl * Cc + c) * Ll;

    // issue all key loads first (stay in flight during the threshold bitonic)
    unsigned int key[32];
    #pragma unroll
    for (int j = 0; j < 8; j++) {
        float4 v = *(const float4*)(col + j * 1024 + tid * 4);
        key[j * 4 + 0] = f2key(v.x); key[j * 4 + 1] = f2key(v.y);
        key[j * 4 + 2] = f2key(v.z); key[j * 4 + 3] = f2key(v.w);
    }

    if (tid < 64) {  // wave 0: fold 128 tile maxima -> 64 super-tiles, bitonic, take 32nd-largest
        float a0 = S[((size_t)pl * NBLK + 2 * tid) * Cc + c];
        float a1 = S[((size_t)pl * NBLK + 2 * tid + 1) * Cc + c];
        unsigned int k2 = f2key(fmaxf(a0, a1));
        #pragma unroll
        for (int kk = 2; kk <= 64; kk <<= 1) {
            #pragma unroll
            for (int j = kk >> 1; j > 0; j >>= 1) {
                unsigned int o = (unsigned int)__shfl_xor((int)k2, j);
                bool up = ((tid & kk) == 0);
                bool hi = (tid & j) != 0;
                unsigned int mn = k2 < o ? k2 : o;
                unsigned int mx = k2 < o ? o : k2;
                k2 = (up == hi) ? mx : mn;   // ascending within each region
            }
        }
        if (tid == 32) sT = k2;              // ascending lane 32 == 32nd largest
        if (tid == 0)  sCnt = 0u;
    }
    __syncthreads();
    const unsigned int T = sT;

    #pragma unroll
    for (int j = 0; j < 8; j++) {
        int ib = j * 1024 + tid * 4;
        #pragma unroll
        for (int e = 0; e < 4; e++) {
            unsigned int kk = key[j * 4 + e];
            if (kk >= T) {
                unsigned p = atomicAdd(&sCnt, 1u);
                if (p < CAP2) { candK[p] = kk; candI[p] = ib + e; }
            }
        }
    }
    __syncthreads();
    const int cnt = (int)sCnt;

    if (cnt <= CAP2) {
        // exact stable rank among candidates (== global rank for all top-32 elements)
        for (int i = tid; i < cnt; i += 256) {
            unsigned int k = candK[i]; int id = candI[i];
            int rk = 0;
            for (int j2 = 0; j2 < cnt; j2++) {
                unsigned int kj = candK[j2];
                rk += (kj > k || (kj == k && candI[j2] < id)) ? 1 : 0;
            }
            if (rk < 32) comb[rk] = id;
        }
        __syncthreads();
    } else {
        // pathological tie flood: exact serial stable top-32 from the column
        if (tid == 0) {
            unsigned int bk[32]; int bi[32];
            for (int j = 0; j < 32; j++) { bk[j] = 0u; bi[j] = 0; }
            for (int i = 0; i < Ll; i++) {
                unsigned int kk = f2key(col[i]);
                if (kk > bk[31]) {
                    int p2 = 31;
                    while (p2 > 0 && kk > bk[p2 - 1]) {
                        bk[p2] = bk[p2 - 1]; bi[p2] = bi[p2 - 1]; p2--;
                    }
                    bk[p2] = kk; bi[p2] = i;
                }
            }
            for (int j = 0; j < 32; j++) comb[j] = bi[j];
        }
        __syncthreads();
    }

    if (tid < Ww) {
        int v = comb[tid];
        int rank = 0;
        #pragma unroll
        for (int j = 0; j < Ww; j++) rank += (comb[j] < v);
        outIdx[(((size_t)(b * Hh + h)) * Cc + c) * Ww + rank] = (float)v;
    }
}

// ---------------- k3: counting sort by (h,cluster), then gather ----------------
__global__ __launch_bounds__(256) void k3_hist(const int* __restrict__ buckets,
                                               unsigned int* __restrict__ hist) {
    __shared__ unsigned int lh[256];
    const int tid = threadIdx.x;
    lh[tid] = 0;
    __syncthreads();
    int i = blockIdx.x * 256 + tid;
    int bk = buckets[i];
    atomicAdd(&lh[bk], 1u);
    __syncthreads();
    int h = (i >> 13) & 7;   // block spans 256 tokens of one (b,h)
    if (lh[tid]) atomicAdd(&hist[h * 256 + tid], lh[tid]);
}

__global__ __launch_bounds__(256) void k3_scan(const unsigned int* __restrict__ hist,
                                               unsigned int* __restrict__ offs,
                                               unsigned int* __restrict__ cursor) {
    __shared__ unsigned int ps[256];
    const int tid = threadIdx.x;
    unsigned int loc[8];
    unsigned s = 0;
    #pragma unroll
    for (int k = 0; k < 8; k++) { loc[k] = hist[tid * 8 + k]; s += loc[k]; }
    ps[tid] = s;
    __syncthreads();
    for (int off = 1; off < 256; off <<= 1) {
        unsigned v = (tid >= off) ? ps[tid - off] : 0;
        __syncthreads();
        ps[tid] += v;
        __syncthreads();
    }
    unsigned base = ps[tid] - s;  // exclusive
    #pragma unroll
    for (int k = 0; k < 8; k++) {
        offs[tid * 8 + k] = base;
        cursor[tid * 8 + k] = base;
        base += loc[k];
    }
    if (tid == 255) offs[2048] = ps[255];
}

__global__ __launch_bounds__(256) void k3_scatter(const int* __restrict__ buckets,
                                                  unsigned int* __restrict__ cursor,
                                                  unsigned int* __restrict__ sortedTok) {
    int i = blockIdx.x * 256 + threadIdx.x;
    int bk = buckets[i];
    int h = (i >> 13) & 7, b = i >> 16, l = i & 8191;
    unsigned pos = atomicAdd(&cursor[h * 256 + bk], 1u);
    sortedTok[pos] = (unsigned)((b << 13) | l);
}

// MLP-restructured gather: lane = (token-slot tl = lane>>4, dim-quad q = lane&15).
__global__ __launch_bounds__(256) void k3_gather(const float* __restrict__ x,
                                                 const float* __restrict__ means,
                                                 const unsigned int* __restrict__ offs,
                                                 const unsigned int* __restrict__ sortedTok,
                                                 float* __restrict__ outMeans) {
    __shared__ __align__(16) float part[4][64];
    const int tid = threadIdx.x;
    const int w = tid >> 6;          // wave 0..3
    const int lane = tid & 63;
    const int tl = lane >> 4;        // token slot within wave 0..3
    const int q  = lane & 15;        // dim quad 0..15 (handles d = 4q..4q+3)
    const int bin = blockIdx.x;
    const int h = bin >> 8, cc = bin & 255;
    const unsigned s0 = offs[bin], s1 = offs[bin + 1];
    const int n = (int)(s1 - s0);

    float4 a0 = make_float4(0.f, 0.f, 0.f, 0.f);
    float4 a1 = make_float4(0.f, 0.f, 0.f, 0.f);
    int j = w * 4 + tl;              // this slot handles j ≡ w*4+tl (mod 16)
    for (; j + 16 < n; j += 32) {    // 2 tokens in flight per slot
        unsigned e0 = sortedTok[s0 + j];
        unsigned e1 = sortedTok[s0 + j + 16];
        const float* p0 = x + (((size_t)((int)(e0 >> 13) * Hh + h)) * Ll + (e0 & 8191)) * Dd + q * 4;
        const float* p1 = x + (((size_t)((int)(e1 >> 13) * Hh + h)) * Ll + (e1 & 8191)) * Dd + q * 4;
        float4 v0 = *(const float4*)p0;
        float4 v1 = *(const float4*)p1;
        a0.x += v0.x; a0.y += v0.y; a0.z += v0.z; a0.w += v0.w;
        a1.x += v1.x; a1.y += v1.y; a1.z += v1.z; a1.w += v1.w;
    }
    for (; j < n; j += 16) {         // at most one leftover token per slot
        unsigned e = sortedTok[s0 + j];
        const float* p = x + (((size_t)((int)(e >> 13) * Hh + h)) * Ll + (e & 8191)) * Dd + q * 4;
        float4 v = *(const float4*)p;
        a0.x += v.x; a0.y += v.y; a0.z += v.z; a0.w += v.w;
    }
    a0.x += a1.x; a0.y += a1.y; a0.z += a1.z; a0.w += a1.w;

    // reduce across the 4 token slots (lane bits 4 and 5)
    #pragma unroll
    for (int off = 16; off <= 32; off <<= 1) {
        a0.x += __shfl_xor(a0.x, off);
        a0.y += __shfl_xor(a0.y, off);
        a0.z += __shfl_xor(a0.z, off);
        a0.w += __shfl_xor(a0.w, off);
    }
    if (tl == 0) *(float4*)&part[w][q * 4] = a0;
    __syncthreads();

    if (tid < 64) {
        const int d = tid;
        float s = part[0][d] + part[1][d] + part[2][d] + part[3][d];
        float t = s * s;
        #pragma unroll
        for (int off = 32; off; off >>= 1) t += __shfl_xor(t, off);
        float nrm = sqrtf(t);
        float outv = (n == 0) ? means[((size_t)(h * Cc + cc)) * Dd + d]
                              : s / fmaxf(nrm, 1e-12f);
        outMeans[((size_t)(h * Cc + cc)) * Dd + d] = outv;
    }
}

// ---------------- k4: loss reduction ----------------
__global__ __launch_bounds__(256) void k4_loss(const float* __restrict__ lossP,
                                               float* __restrict__ out) {
    __shared__ float red[256];
    const int tid = threadIdx.x;
    float s = 0.f;
    for (int i = tid; i < Bb * Hh * NBLK; i += 256) s += lossP[i];
    red[tid] = s;
    __syncthreads();
    for (int off = 128; off; off >>= 1) {
        if (tid < off) red[tid] += red[tid + off];
        __syncthreads();
    }
    if (tid == 0)
        out[(size_t)Bb * Hh * Cc * Ww] = red[0] * (1e-4f / (float)((size_t)Bb * Hh * Ll * Dd));
}

extern "C" void kernel_launch(void* const* d_in, const int* in_sizes, int n_in,
                              void* d_out, int out_size, void* d_ws, size_t ws_size,
                              hipStream_t stream) {
    (void)in_sizes; (void)n_in; (void)out_size;
    const float* x = (const float*)d_in[0];
    const float* means = (const float*)d_in[1];
    float* out = (float*)d_out;

    char* ws = (char*)d_ws;
    float* lossP = (float*)ws;                              // 4096 floats (16 KB)
    int* buckets = (int*)(ws + 16384);                      // 1 MB
    unsigned int* hist = (unsigned int*)(ws + 16384 + 1048576);      // 2048
    unsigned int* offs = hist + 2048;                       // 2049
    unsigned int* cursor = offs + 2049;                     // 2048
    unsigned int* sortedTok = cursor + 2048;                // 262144 (1 MB)
    size_t base = 16384 + 1048576 + 4ull * (2048 + 2049 + 2048) + 4ull * 262144;
    base = (base + 255) & ~255ull;
    float* S = (float*)(ws + base);                         // 32 planes * 128 * 256 f = 4 MB (max)
    size_t dbase = base + 4ull * 32 * NBLK * Cc;
    dbase = (dbase + 255) & ~255ull;
    float* distT = (float*)(ws + dbase);
    const size_t perPlane = (size_t)Cc * Ll * 4;            // 8 MB per (b,h) plane

    int bStep = 4, hStep = 8;
    if (dbase + (size_t)bStep * hStep * perPlane > ws_size) bStep = 1;
    while (hStep > 1 && dbase + (size_t)bStep * hStep * perPlane > ws_size) hStep >>= 1;

    hipMemsetAsync(hist, 0, 2048 * 4, stream);

    const int IDXN = Bb * Hh * Cc * Ww;  // 262144
    for (int b0 = 0; b0 < Bb; b0 += bStep) {
        for (int h0 = 0; h0 < Hh; h0 += hStep) {
            k1_gemm<<<dim3(Ll / TL, hStep, bStep), 256, 0, stream>>>(x, means, distT, S, buckets, lossP, b0, h0);
            k2_sel<<<dim3(Cc, hStep, bStep), 256, 0, stream>>>(distT, S, out, b0, h0);
        }
    }
    k3_hist<<<1024, 256, 0, stream>>>(buckets, hist);
    k3_scan<<<1, 256, 0, stream>>>(hist, offs, cursor);
    k3_scatter<<<1024, 256, 0, stream>>>(buckets, cursor, sortedTok);
    k3_gather<<<Hh * Cc, 256, 0, stream>>>(x, means, offs, sortedTok, out + IDXN + 1);
    k4_loss<<<1, 256, 0, stream>>>(lossP, out);
}

// Round 7
// 443.892 us; speedup vs baseline: 1.7308x; 1.0311x over previous
//
#include <hip/hip_runtime.h>
#include <hip/hip_bf16.h>

#define Bb 4
#define Hh 8
#define Ll 8192
#define Dd 64
#define Cc 256
#define Ww 32
#define TL 128     // tokens per k1 block
#define NBLK 64    // Ll / TL tiles per plane
#define CAP2 2048  // k2_sel LDS candidate capacity

// ---------------- k1: dists GEMM (8x8 tile, 2 passes, dists held in VGPRs) ----------------
// grid (64, hStep, bStep), block 256, launch_bounds(256,2) -> ~200 VGPR, 2 waves/SIMD.
// All distT stores moved to a barrier-free tail: argmax/loss barriers fire BEFORE any
// global store is issued, so no mid-kernel vmcnt(0) store drain (r1-r6 all had
// stores->barrier per pass; suspected ~20% stall per guide "barrier drain").
__global__ __launch_bounds__(256, 2) void k1_gemm(const float* __restrict__ x,
                                                  const float* __restrict__ means,
                                                  float* __restrict__ distT,
                                                  float* __restrict__ S,
                                                  int* __restrict__ buckets,
                                                  float* __restrict__ lossP,
                                                  int b0, int h0) {
    __shared__ __align__(16) float ms[128 * 68];   // 34.8 KB
    __shared__ __align__(16) float xs[TL * 68];    // 34.8 KB
    __shared__ float pv[TL * 4];
    __shared__ int   pc[TL * 4];
    __shared__ float msq[256];
    __shared__ float lossAcc;

    const int tid = threadIdx.x;
    const int hl  = blockIdx.y, bz = blockIdx.z;
    const int h   = h0 + hl,    b  = b0 + bz;
    const int l0  = blockIdx.x * TL;
    const int tg  = tid & 15;    // tokens t = tg + 16*jt, jt<8
    const int cg  = tid >> 4;    // clusters c = cg + 16*jl (+128 for pass B), jl<8

    if (tid == 0) lossAcc = 0.f;

    const float* xbase = x + (((size_t)(b * Hh + h)) * Ll + l0) * Dd;
    for (int j = tid; j < TL * 16; j += 256) {
        int t = j >> 4, k4 = (j & 15) << 2;
        *(float4*)&xs[t * 68 + k4] = *(const float4*)(xbase + t * Dd + k4);
    }

    float accA[8][8], accB[8][8];

    // ---- pass A: clusters 0..127 ----
    {
        const float* mbase = means + ((size_t)h * Cc) * Dd;
        for (int j = tid; j < 128 * 16; j += 256) {
            int r = j >> 4, k4 = (j & 15) << 2;
            *(float4*)&ms[r * 68 + k4] = *(const float4*)(mbase + r * Dd + k4);
        }
        __syncthreads();   // covers xs + msA staging
        if (tid < 128) {
            float s = 0.f;
            #pragma unroll
            for (int k = 0; k < 64; k += 4) {
                float4 m = *(const float4*)&ms[tid * 68 + k];
                s = fmaf(m.x, m.x, s); s = fmaf(m.y, m.y, s);
                s = fmaf(m.z, m.z, s); s = fmaf(m.w, m.w, s);
            }
            msq[tid] = s;
        }
        #pragma unroll
        for (int jt = 0; jt < 8; jt++)
            #pragma unroll
            for (int jl = 0; jl < 8; jl++) accA[jt][jl] = 0.f;
        #pragma unroll 4
        for (int k = 0; k < 64; k += 4) {
            float4 xa[8];
            #pragma unroll
            for (int jt = 0; jt < 8; jt++) xa[jt] = *(const float4*)&xs[(tg + 16 * jt) * 68 + k];
            #pragma unroll
            for (int jl = 0; jl < 8; jl++) {
                float4 m = *(const float4*)&ms[(cg + 16 * jl) * 68 + k];
                #pragma unroll
                for (int jt = 0; jt < 8; jt++) {
                    float a = accA[jt][jl];
                    a = fmaf(xa[jt].x, m.x, a); a = fmaf(xa[jt].y, m.y, a);
                    a = fmaf(xa[jt].z, m.z, a); a = fmaf(xa[jt].w, m.w, a);
                    accA[jt][jl] = a;
                }
            }
        }
        __syncthreads();   // all reads of msA done (no stores pending: drain-free)
    }

    // ---- pass B: clusters 128..255 ----
    {
        const float* mbase = means + ((size_t)h * Cc + 128) * Dd;
        for (int j = tid; j < 128 * 16; j += 256) {
            int r = j >> 4, k4 = (j & 15) << 2;
            *(float4*)&ms[r * 68 + k4] = *(const float4*)(mbase + r * Dd + k4);
        }
        __syncthreads();
        if (tid < 128) {
            float s = 0.f;
            #pragma unroll
            for (int k = 0; k < 64; k += 4) {
                float4 m = *(const float4*)&ms[tid * 68 + k];
                s = fmaf(m.x, m.x, s); s = fmaf(m.y, m.y, s);
                s = fmaf(m.z, m.z, s); s = fmaf(m.w, m.w, s);
            }
            msq[128 + tid] = s;
        }
        #pragma unroll
        for (int jt = 0; jt < 8; jt++)
            #pragma unroll
            for (int jl = 0; jl < 8; jl++) accB[jt][jl] = 0.f;
        #pragma unroll 4
        for (int k = 0; k < 64; k += 4) {
            float4 xa[8];
            #pragma unroll
            for (int jt = 0; jt < 8; jt++) xa[jt] = *(const float4*)&xs[(tg + 16 * jt) * 68 + k];
            #pragma unroll
            for (int jl = 0; jl < 8; jl++) {
                float4 m = *(const float4*)&ms[(cg + 16 * jl) * 68 + k];
                #pragma unroll
                for (int jt = 0; jt < 8; jt++) {
                    float a = accB[jt][jl];
                    a = fmaf(xa[jt].x, m.x, a); a = fmaf(xa[jt].y, m.y, a);
                    a = fmaf(xa[jt].z, m.z, a); a = fmaf(xa[jt].w, m.w, a);
                    accB[jt][jl] = a;
                }
            }
        }
    }

    // ---- tail 1: argmax + loss (barriers fire with zero pending stores) ----
    #pragma unroll
    for (int jt = 0; jt < 8; jt++) {
        float bv = -3.4e38f; int bc = 0;
        #pragma unroll
        for (int jl = 0; jl < 8; jl++) {           // ascending c: strict > keeps lowest c
            float v = accA[jt][jl];
            if (v > bv) { bv = v; bc = cg + 16 * jl; }
        }
        #pragma unroll
        for (int jl = 0; jl < 8; jl++) {
            float v = accB[jt][jl];
            if (v > bv) { bv = v; bc = cg + 16 * jl + 128; }
        }
        #pragma unroll
        for (int off = 16; off <= 32; off <<= 1) {
            float ov = __shfl_xor(bv, off);
            int   oc = __shfl_xor(bc, off);
            if (ov > bv || (ov == bv && oc < bc)) { bv = ov; bc = oc; }
        }
        if ((tid & 48) == 0) { int t = tg + 16 * jt; pv[t * 4 + (tid >> 6)] = bv; pc[t * 4 + (tid >> 6)] = bc; }
    }
    __syncthreads();

    if (tid < TL) {
        int t = tid;
        float bv = pv[t * 4]; int bc = pc[t * 4];
        #pragma unroll
        for (int g = 1; g < 4; g++) {
            float v = pv[t * 4 + g]; int c2 = pc[t * 4 + g];
            if (v > bv || (v == bv && c2 < bc)) { bv = v; bc = c2; }
        }
        float ss = 0.f;
        #pragma unroll
        for (int k = 0; k < 64; k += 4) {
            float4 u = *(const float4*)&xs[t * 68 + k];
            ss = fmaf(u.x, u.x, ss); ss = fmaf(u.y, u.y, ss);
            ss = fmaf(u.z, u.z, ss); ss = fmaf(u.w, u.w, ss);
        }
        buckets[((size_t)(b * Hh + h)) * Ll + l0 + t] = bc;
        atomicAdd(&lossAcc, ss - 2.f * bv + msq[bc]);
    }
    __syncthreads();
    if (tid == 0) lossP[(b * Hh + h) * NBLK + blockIdx.x] = lossAcc;

    // ---- tail 2: S tile-max summary (shuffles only, no barrier) ----
    const size_t srow = (((size_t)(bz * gridDim.y + hl)) * NBLK + blockIdx.x) * Cc;
    #pragma unroll
    for (int jl = 0; jl < 8; jl++) {
        float cmA = accA[0][jl], cmB = accB[0][jl];
        #pragma unroll
        for (int jt = 1; jt < 8; jt++) { cmA = fmaxf(cmA, accA[jt][jl]); cmB = fmaxf(cmB, accB[jt][jl]); }
        #pragma unroll
        for (int off = 1; off < 16; off <<= 1) {
            cmA = fmaxf(cmA, __shfl_xor(cmA, off));
            cmB = fmaxf(cmB, __shfl_xor(cmB, off));
        }
        if (tg == 0) {
            S[srow + cg + 16 * jl] = cmA;
            S[srow + cg + 16 * jl + 128] = cmB;
        }
    }

    // ---- tail 3: all distT stores last; drain at kernel exit, no barrier behind them ----
    const size_t pbase = ((size_t)(bz * gridDim.y + hl)) * Cc;
    float* dbaseA = distT + (pbase + cg) * Ll + l0 + tg;
    #pragma unroll
    for (int jl = 0; jl < 8; jl++) {
        float* rowA = dbaseA + (size_t)(16 * jl) * Ll;
        float* rowB = dbaseA + (size_t)(16 * jl + 128) * Ll;
        #pragma unroll
        for (int jt = 0; jt < 8; jt++) {
            rowA[16 * jt] = accA[jt][jl];
            rowB[16 * jt] = accB[jt][jl];
        }
    }
}

// ---------------- k2_sel: fused threshold + stream-compact + exact stable rank ----------------
__device__ __forceinline__ unsigned int f2key(float f) {
    unsigned int u = __float_as_uint(f);
    return (u & 0x80000000u) ? ~u : (u | 0x80000000u);
}

// grid (Cc, hStep, bStep), block 256. Wave 0 computes T inline (bitonic-64 of the 64
// tile maxima) while all threads' key loads are in flight. T = 32nd-largest of 64
// disjoint 128-token tile maxima => >=32 distinct tokens have key >= T => top-32
// subset of candidates; rank-in-candidates == global rank. Exact (field-verified r4-r6).
__global__ __launch_bounds__(256) void k2_sel(const float* __restrict__ distT,
                                              const float* __restrict__ S,
                                              float* __restrict__ outIdx,
                                              int b0, int h0) {
    __shared__ unsigned int sT, sCnt;
    __shared__ unsigned int candK[CAP2];
    __shared__ int candI[CAP2];
    __shared__ int comb[32];

    const int tid = threadIdx.x;
    const int c = blockIdx.x, hl = blockIdx.y, bz = blockIdx.z;
    const int h = h0 + hl, b = b0 + bz;
    const int pl = bz * gridDim.y + hl;                   // pass-local plane
    const float* col = distT + ((size_t)pl * Cc + c) * Ll;

    unsigned int key[32];
    #pragma unroll
    for (int j = 0; j < 8; j++) {
        float4 v = *(const float4*)(col + j * 1024 + tid * 4);
        key[j * 4 + 0] = f2key(v.x); key[j * 4 + 1] = f2key(v.y);
        key[j * 4 + 2] = f2key(v.z); key[j * 4 + 3] = f2key(v.w);
    }

    if (tid < 64) {  // wave 0: bitonic sort the 64 tile maxima; take 32nd-largest
        unsigned int k2 = f2key(S[((size_t)pl * NBLK + tid) * Cc + c]);
        #pragma unroll
        for (int kk = 2; kk <= 64; kk <<= 1) {
            #pragma unroll
            for (int j = kk >> 1; j > 0; j >>= 1) {
                unsigned int o = (unsigned int)__shfl_xor((int)k2, j);
                bool up = ((tid & kk) == 0);
                bool hi = (tid & j) != 0;
                unsigned int mn = k2 < o ? k2 : o;
                unsigned int mx = k2 < o ? o : k2;
                k2 = (up == hi) ? mx : mn;   // ascending within each region
            }
        }
        if (tid == 32) sT = k2;              // ascending lane 32 == 32nd largest
        if (tid == 0)  sCnt = 0u;
    }
    __syncthreads();
    const unsigned int T = sT;

    #pragma unroll
    for (int j = 0; j < 8; j++) {
        int ib = j * 1024 + tid * 4;
        #pragma unroll
        for (int e = 0; e < 4; e++) {
            unsigned int kk = key[j * 4 + e];
            if (kk >= T) {
                unsigned p = atomicAdd(&sCnt, 1u);
                if (p < CAP2) { candK[p] = kk; candI[p] = ib + e; }
            }
        }
    }
    __syncthreads();
    const int cnt = (int)sCnt;

    if (cnt <= CAP2) {
        for (int i = tid; i < cnt; i += 256) {
            unsigned int k = candK[i]; int id = candI[i];
            int rk = 0;
            for (int j2 = 0; j2 < cnt; j2++) {
                unsigned int kj = candK[j2];
                rk += (kj > k || (kj == k && candI[j2] < id)) ? 1 : 0;
            }
            if (rk < 32) comb[rk] = id;
        }
        __syncthreads();
    } else {
        if (tid == 0) {   // pathological tie flood: exact serial stable top-32
            unsigned int bk[32]; int bi[32];
            for (int j = 0; j < 32; j++) { bk[j] = 0u; bi[j] = 0; }
            for (int i = 0; i < Ll; i++) {
                unsigned int kk = f2key(col[i]);
                if (kk > bk[31]) {
                    int p2 = 31;
                    while (p2 > 0 && kk > bk[p2 - 1]) {
                        bk[p2] = bk[p2 - 1]; bi[p2] = bi[p2 - 1]; p2--;
                    }
                    bk[p2] = kk; bi[p2] = i;
                }
            }
            for (int j = 0; j < 32; j++) comb[j] = bi[j];
        }
        __syncthreads();
    }

    if (tid < Ww) {
        int v = comb[tid];
        int rank = 0;
        #pragma unroll
        for (int j = 0; j < Ww; j++) rank += (comb[j] < v);
        outIdx[(((size_t)(b * Hh + h)) * Cc + c) * Ww + rank] = (float)v;
    }
}

// ---------------- k3: counting sort by (h,cluster), then gather ----------------
__global__ __launch_bounds__(256) void k3_hist(const int* __restrict__ buckets,
                                               unsigned int* __restrict__ hist) {
    __shared__ unsigned int lh[256];
    const int tid = threadIdx.x;
    lh[tid] = 0;
    __syncthreads();
    int i = blockIdx.x * 256 + tid;
    int bk = buckets[i];
    atomicAdd(&lh[bk], 1u);
    __syncthreads();
    int h = (i >> 13) & 7;   // block spans 256 tokens of one (b,h)
    if (lh[tid]) atomicAdd(&hist[h * 256 + tid], lh[tid]);
}

__global__ __launch_bounds__(256) void k3_scan(const unsigned int* __restrict__ hist,
                                               unsigned int* __restrict__ offs,
                                               unsigned int* __restrict__ cursor) {
    __shared__ unsigned int ps[256];
    const int tid = threadIdx.x;
    unsigned int loc[8];
    unsigned s = 0;
    #pragma unroll
    for (int k = 0; k < 8; k++) { loc[k] = hist[tid * 8 + k]; s += loc[k]; }
    ps[tid] = s;
    __syncthreads();
    for (int off = 1; off < 256; off <<= 1) {
        unsigned v = (tid >= off) ? ps[tid - off] : 0;
        __syncthreads();
        ps[tid] += v;
        __syncthreads();
    }
    unsigned base = ps[tid] - s;  // exclusive
    #pragma unroll
    for (int k = 0; k < 8; k++) {
        offs[tid * 8 + k] = base;
        cursor[tid * 8 + k] = base;
        base += loc[k];
    }
    if (tid == 255) offs[2048] = ps[255];
}

__global__ __launch_bounds__(256) void k3_scatter(const int* __restrict__ buckets,
                                                  unsigned int* __restrict__ cursor,
                                                  unsigned int* __restrict__ sortedTok) {
    int i = blockIdx.x * 256 + threadIdx.x;
    int bk = buckets[i];
    int h = (i >> 13) & 7, b = i >> 16, l = i & 8191;
    unsigned pos = atomicAdd(&cursor[h * 256 + bk], 1u);
    sortedTok[pos] = (unsigned)((b << 13) | l);
}

// MLP-restructured gather: lane = (token-slot tl = lane>>4, dim-quad q = lane&15).
__global__ __launch_bounds__(256) void k3_gather(const float* __restrict__ x,
                                                 const float* __restrict__ means,
                                                 const unsigned int* __restrict__ offs,
                                                 const unsigned int* __restrict__ sortedTok,
                                                 float* __restrict__ outMeans) {
    __shared__ __align__(16) float part[4][64];
    const int tid = threadIdx.x;
    const int w = tid >> 6;          // wave 0..3
    const int lane = tid & 63;
    const int tl = lane >> 4;        // token slot within wave 0..3
    const int q  = lane & 15;        // dim quad 0..15 (handles d = 4q..4q+3)
    const int bin = blockIdx.x;
    const int h = bin >> 8, cc = bin & 255;
    const unsigned s0 = offs[bin], s1 = offs[bin + 1];
    const int n = (int)(s1 - s0);

    float4 a0 = make_float4(0.f, 0.f, 0.f, 0.f);
    float4 a1 = make_float4(0.f, 0.f, 0.f, 0.f);
    int j = w * 4 + tl;              // this slot handles j ≡ w*4+tl (mod 16)
    for (; j + 16 < n; j += 32) {    // 2 tokens in flight per slot
        unsigned e0 = sortedTok[s0 + j];
        unsigned e1 = sortedTok[s0 + j + 16];
        const float* p0 = x + (((size_t)((int)(e0 >> 13) * Hh + h)) * Ll + (e0 & 8191)) * Dd + q * 4;
        const float* p1 = x + (((size_t)((int)(e1 >> 13) * Hh + h)) * Ll + (e1 & 8191)) * Dd + q * 4;
        float4 v0 = *(const float4*)p0;
        float4 v1 = *(const float4*)p1;
        a0.x += v0.x; a0.y += v0.y; a0.z += v0.z; a0.w += v0.w;
        a1.x += v1.x; a1.y += v1.y; a1.z += v1.z; a1.w += v1.w;
    }
    for (; j < n; j += 16) {         // at most one leftover token per slot
        unsigned e = sortedTok[s0 + j];
        const float* p = x + (((size_t)((int)(e >> 13) * Hh + h)) * Ll + (e & 8191)) * Dd + q * 4;
        float4 v = *(const float4*)p;
        a0.x += v.x; a0.y += v.y; a0.z += v.z; a0.w += v.w;
    }
    a0.x += a1.x; a0.y += a1.y; a0.z += a1.z; a0.w += a1.w;

    // reduce across the 4 token slots (lane bits 4 and 5)
    #pragma unroll
    for (int off = 16; off <= 32; off <<= 1) {
        a0.x += __shfl_xor(a0.x, off);
        a0.y += __shfl_xor(a0.y, off);
        a0.z += __shfl_xor(a0.z, off);
        a0.w += __shfl_xor(a0.w, off);
    }
    if (tl == 0) *(float4*)&part[w][q * 4] = a0;
    __syncthreads();

    if (tid < 64) {
        const int d = tid;
        float s = part[0][d] + part[1][d] + part[2][d] + part[3][d];
        float t = s * s;
        #pragma unroll
        for (int off = 32; off; off >>= 1) t += __shfl_xor(t, off);
        float nrm = sqrtf(t);
        float outv = (n == 0) ? means[((size_t)(h * Cc + cc)) * Dd + d]
                              : s / fmaxf(nrm, 1e-12f);
        outMeans[((size_t)(h * Cc + cc)) * Dd + d] = outv;
    }
}

// ---------------- k4: loss reduction ----------------
__global__ __launch_bounds__(256) void k4_loss(const float* __restrict__ lossP,
                                               float* __restrict__ out) {
    __shared__ float red[256];
    const int tid = threadIdx.x;
    float s = 0.f;
    for (int i = tid; i < Bb * Hh * NBLK; i += 256) s += lossP[i];
    red[tid] = s;
    __syncthreads();
    for (int off = 128; off; off >>= 1) {
        if (tid < off) red[tid] += red[tid + off];
        __syncthreads();
    }
    if (tid == 0)
        out[(size_t)Bb * Hh * Cc * Ww] = red[0] * (1e-4f / (float)((size_t)Bb * Hh * Ll * Dd));
}

extern "C" void kernel_launch(void* const* d_in, const int* in_sizes, int n_in,
                              void* d_out, int out_size, void* d_ws, size_t ws_size,
                              hipStream_t stream) {
    (void)in_sizes; (void)n_in; (void)out_size;
    const float* x = (const float*)d_in[0];
    const float* means = (const float*)d_in[1];
    float* out = (float*)d_out;

    char* ws = (char*)d_ws;
    float* lossP = (float*)ws;                              // 2048 floats (8 KB)
    int* buckets = (int*)(ws + 8192);                       // 1 MB
    unsigned int* hist = (unsigned int*)(ws + 8192 + 1048576);       // 2048
    unsigned int* offs = hist + 2048;                       // 2049
    unsigned int* cursor = offs + 2049;                     // 2048
    unsigned int* sortedTok = cursor + 2048;                // 262144 (1 MB)
    size_t base = 8192 + 1048576 + 4ull * (2048 + 2049 + 2048) + 4ull * 262144;
    base = (base + 255) & ~255ull;
    float* S = (float*)(ws + base);                         // 32 planes * 64 * 256 f = 2 MB (max)
    size_t dbase = base + 4ull * 32 * NBLK * Cc;
    dbase = (dbase + 255) & ~255ull;
    float* distT = (float*)(ws + dbase);
    const size_t perPlane = (size_t)Cc * Ll * 4;            // 8 MB per (b,h) plane

    int bStep = 4, hStep = 8;
    if (dbase + (size_t)bStep * hStep * perPlane > ws_size) bStep = 1;
    while (hStep > 1 && dbase + (size_t)bStep * hStep * perPlane > ws_size) hStep >>= 1;

    hipMemsetAsync(hist, 0, 2048 * 4, stream);

    const int IDXN = Bb * Hh * Cc * Ww;  // 262144
    for (int b0 = 0; b0 < Bb; b0 += bStep) {
        for (int h0 = 0; h0 < Hh; h0 += hStep) {
            k1_gemm<<<dim3(NBLK, hStep, bStep), 256, 0, stream>>>(x, means, distT, S, buckets, lossP, b0, h0);
            k2_sel<<<dim3(Cc, hStep, bStep), 256, 0, stream>>>(distT, S, out, b0, h0);
        }
    }
    k3_hist<<<1024, 256, 0, stream>>>(buckets, hist);
    k3_scan<<<1, 256, 0, stream>>>(hist, offs, cursor);
    k3_scatter<<<1024, 256, 0, stream>>>(buckets, cursor, sortedTok);
    k3_gather<<<Hh * Cc, 256, 0, stream>>>(x, means, offs, sortedTok, out + IDXN + 1);
    k4_loss<<<1, 256, 0, stream>>>(lossP, out);
}